// Round 1
// baseline (148.936 us; speedup 1.0000x reference)
//
#include <hip/hip_runtime.h>

#define TT 4096

// ws float offsets (total 1,158,868 floats = 4.64 MB; assumes ws_size >= 5 MB)
#define OFF_GPART 0        // [32][2][256]
#define OFF_Q     16384    // [2][4096][16]
#define OFF_K     147456
#define OFF_V     278528
#define OFF_Y     409600   // [48][4096]
#define OFF_C0    606208   // [5][24][4094]
#define OFF_C1    1097488  // [5][12][1023]

__device__ __forceinline__ float relu6f(float v){ return fminf(fmaxf(v, 0.f), 6.f); }

// ---------------- G partials: G[i][j] = sum_t wav[t]*e_i[t]*e_j[t] ----------------
__global__ __launch_bounds__(256) void k_gpart(const float* __restrict__ x, float* __restrict__ ws){
  const int b = blockIdx.x, tid = threadIdx.x;        // 32 blocks x 128 t
  const int i = tid >> 4, j = tid & 15;
  const float* ei = x + (size_t)(1+i)*TT;
  const float* ej = x + (size_t)(1+j)*TT;
  const float* wA = x;                 // row 0
  const float* wB = x + (size_t)17*TT; // row 17
  float gA = 0.f, gB = 0.f;
  const int t0 = b*128;
  for (int t = t0; t < t0+128; ++t){
    float p = ei[t]*ej[t];
    gA = fmaf(wA[t], p, gA);
    gB = fmaf(wB[t], p, gB);
  }
  ws[OFF_GPART + b*512 + tid]       = gA;
  ws[OFF_GPART + b*512 + 256 + tid] = gB;
}

// ---------------- QKV: w2 = G @ (wav*e); Q=relu6(W0 e+b0); K=relu6(W1 w2+b1); V=relu6(W2 w2+b2)
__global__ __launch_bounds__(256) void k_qkv(const float* __restrict__ x,
    const float* __restrict__ cm1W, const float* __restrict__ cm1b,
    const float* __restrict__ cm2W, const float* __restrict__ cm2b,
    float* __restrict__ ws){
  __shared__ float4 sG4[64];
  __shared__ float4 sW0[64], sW1[64], sW2[64];
  __shared__ float sB[48];
  const int b = blockIdx.x;           // 32 blocks: 0..15 cm0, 16..31 cm1
  const int cm = b >> 4;
  const int tid = threadIdx.x;
  // reduce G partials (fixed order -> deterministic)
  float g = 0.f;
  for (int blk = 0; blk < 32; ++blk) g += ws[OFF_GPART + blk*512 + cm*256 + tid];
  ((float*)sG4)[tid] = g;
  const float* W  = cm ? cm2W : cm1W;
  const float* Bb = cm ? cm2b : cm1b;
  ((float*)sW0)[tid] = W[tid];
  ((float*)sW1)[tid] = W[256 + tid];
  ((float*)sW2)[tid] = W[512 + tid];
  if (tid < 48) sB[tid] = Bb[tid];
  __syncthreads();

  const int t = (b & 15)*256 + tid;
  float e[16], p[16], w2[16];
  const float wav = x[(size_t)(cm ? 17 : 0)*TT + t];
  #pragma unroll
  for (int d = 0; d < 16; ++d){ e[d] = x[(size_t)(1+d)*TT + t]; p[d] = wav * e[d]; }

  #pragma unroll
  for (int c = 0; c < 16; ++c){
    float a = 0.f;
    #pragma unroll
    for (int dv = 0; dv < 4; ++dv){
      float4 gv = sG4[c*4+dv];
      a = fmaf(gv.x, p[4*dv+0], a); a = fmaf(gv.y, p[4*dv+1], a);
      a = fmaf(gv.z, p[4*dv+2], a); a = fmaf(gv.w, p[4*dv+3], a);
    }
    w2[c] = a;
  }
  float q[16], kk[16], vv[16];
  #pragma unroll
  for (int c = 0; c < 16; ++c){
    float aq = sB[c], ak = sB[16+c], av = sB[32+c];
    #pragma unroll
    for (int dv = 0; dv < 4; ++dv){
      float4 w0 = sW0[c*4+dv], w1 = sW1[c*4+dv], w3 = sW2[c*4+dv];
      aq = fmaf(w0.x, e[4*dv+0], aq);  aq = fmaf(w0.y, e[4*dv+1], aq);
      aq = fmaf(w0.z, e[4*dv+2], aq);  aq = fmaf(w0.w, e[4*dv+3], aq);
      ak = fmaf(w1.x, w2[4*dv+0], ak); ak = fmaf(w1.y, w2[4*dv+1], ak);
      ak = fmaf(w1.z, w2[4*dv+2], ak); ak = fmaf(w1.w, w2[4*dv+3], ak);
      av = fmaf(w3.x, w2[4*dv+0], av); av = fmaf(w3.y, w2[4*dv+1], av);
      av = fmaf(w3.z, w2[4*dv+2], av); av = fmaf(w3.w, w2[4*dv+3], av);
    }
    q[c] = relu6f(aq); kk[c] = relu6f(ak); vv[c] = relu6f(av);
  }
  float* Qp = ws + OFF_Q + ((size_t)cm*TT + t)*16;
  float* Kp = ws + OFF_K + ((size_t)cm*TT + t)*16;
  float* Vp = ws + OFF_V + ((size_t)cm*TT + t)*16;
  #pragma unroll
  for (int dv = 0; dv < 4; ++dv){
    reinterpret_cast<float4*>(Qp)[dv] = make_float4(q[4*dv],  q[4*dv+1],  q[4*dv+2],  q[4*dv+3]);
    reinterpret_cast<float4*>(Kp)[dv] = make_float4(kk[4*dv], kk[4*dv+1], kk[4*dv+2], kk[4*dv+3]);
    reinterpret_cast<float4*>(Vp)[dv] = make_float4(vv[4*dv], vv[4*dv+1], vv[4*dv+2], vv[4*dv+3]);
  }
  if (cm == 0){  // y rows 16..31 = eeg2
    #pragma unroll
    for (int d = 0; d < 16; ++d) ws[OFF_Y + (size_t)(16+d)*TT + t] = e[d];
  }
}

#define ACC_SCALE(r, sc, v0, v1, v2, v3) \
  acc[r][0]=fmaf(acc[r][0],sc,v0.x); acc[r][1]=fmaf(acc[r][1],sc,v0.y); \
  acc[r][2]=fmaf(acc[r][2],sc,v0.z); acc[r][3]=fmaf(acc[r][3],sc,v0.w); \
  acc[r][4]=fmaf(acc[r][4],sc,v1.x); acc[r][5]=fmaf(acc[r][5],sc,v1.y); \
  acc[r][6]=fmaf(acc[r][6],sc,v1.z); acc[r][7]=fmaf(acc[r][7],sc,v1.w); \
  acc[r][8]=fmaf(acc[r][8],sc,v2.x); acc[r][9]=fmaf(acc[r][9],sc,v2.y); \
  acc[r][10]=fmaf(acc[r][10],sc,v2.z); acc[r][11]=fmaf(acc[r][11],sc,v2.w); \
  acc[r][12]=fmaf(acc[r][12],sc,v3.x); acc[r][13]=fmaf(acc[r][13],sc,v3.y); \
  acc[r][14]=fmaf(acc[r][14],sc,v3.z); acc[r][15]=fmaf(acc[r][15],sc,v3.w);

#define ACC_ADD(r, pp, v0, v1, v2, v3) \
  acc[r][0]=fmaf(pp,v0.x,acc[r][0]); acc[r][1]=fmaf(pp,v0.y,acc[r][1]); \
  acc[r][2]=fmaf(pp,v0.z,acc[r][2]); acc[r][3]=fmaf(pp,v0.w,acc[r][3]); \
  acc[r][4]=fmaf(pp,v1.x,acc[r][4]); acc[r][5]=fmaf(pp,v1.y,acc[r][5]); \
  acc[r][6]=fmaf(pp,v1.z,acc[r][6]); acc[r][7]=fmaf(pp,v1.w,acc[r][7]); \
  acc[r][8]=fmaf(pp,v2.x,acc[r][8]); acc[r][9]=fmaf(pp,v2.y,acc[r][9]); \
  acc[r][10]=fmaf(pp,v2.z,acc[r][10]); acc[r][11]=fmaf(pp,v2.w,acc[r][11]); \
  acc[r][12]=fmaf(pp,v3.x,acc[r][12]); acc[r][13]=fmaf(pp,v3.y,acc[r][13]); \
  acc[r][14]=fmaf(pp,v3.z,acc[r][14]); acc[r][15]=fmaf(pp,v3.w,acc[r][15]);

#define DOT16(res, r, a0, a1, a2, a3) { \
  float s_ = q[r][0]*a0.x; \
  s_=fmaf(q[r][1],a0.y,s_); s_=fmaf(q[r][2],a0.z,s_); s_=fmaf(q[r][3],a0.w,s_); \
  s_=fmaf(q[r][4],a1.x,s_); s_=fmaf(q[r][5],a1.y,s_); s_=fmaf(q[r][6],a1.z,s_); s_=fmaf(q[r][7],a1.w,s_); \
  s_=fmaf(q[r][8],a2.x,s_); s_=fmaf(q[r][9],a2.y,s_); s_=fmaf(q[r][10],a2.z,s_); s_=fmaf(q[r][11],a2.w,s_); \
  s_=fmaf(q[r][12],a3.x,s_); s_=fmaf(q[r][13],a3.y,s_); s_=fmaf(q[r][14],a3.z,s_); s_=fmaf(q[r][15],a3.w,s_); \
  res = s_; }

// ---------------- attention: y_rows = relu6(W3 @ softmax16(softmaxT(QK^T)@V) + b3)
__global__ __launch_bounds__(256) void k_attn(
    const float* __restrict__ cm1W, const float* __restrict__ cm1b,
    const float* __restrict__ cm2W, const float* __restrict__ cm2b,
    float* __restrict__ ws){
  const int b = blockIdx.x;          // 512 blocks
  const int cm = b >> 8;
  const int tid = threadIdx.x;
  const int wave = tid >> 6;
  const int lane = tid & 63;
  const int t0 = (b & 255)*16 + wave*4;   // 4 queries per wave
  const float* Qc = ws + OFF_Q + (size_t)cm*TT*16;
  const float* Kc = ws + OFF_K + (size_t)cm*TT*16;
  const float* Vc = ws + OFF_V + (size_t)cm*TT*16;

  float q[4][16];
  #pragma unroll
  for (int r = 0; r < 4; ++r){
    const float4* q4 = reinterpret_cast<const float4*>(Qc + (size_t)(t0+r)*16);
    float4 a = q4[0], bq = q4[1], c = q4[2], d = q4[3];
    q[r][0]=a.x;  q[r][1]=a.y;  q[r][2]=a.z;  q[r][3]=a.w;
    q[r][4]=bq.x; q[r][5]=bq.y; q[r][6]=bq.z; q[r][7]=bq.w;
    q[r][8]=c.x;  q[r][9]=c.y;  q[r][10]=c.z; q[r][11]=c.w;
    q[r][12]=d.x; q[r][13]=d.y; q[r][14]=d.z; q[r][15]=d.w;
  }
  float m[4] = {-1e30f,-1e30f,-1e30f,-1e30f};
  float l[4] = {0.f,0.f,0.f,0.f};
  float acc[4][16];
  #pragma unroll
  for (int r = 0; r < 4; ++r)
    #pragma unroll
    for (int d = 0; d < 16; ++d) acc[r][d] = 0.f;

  for (int k = 0; k < 64; ++k){       // lane = key slice; j = k*64+lane
    const int j = k*64 + lane;
    const float4* k4 = reinterpret_cast<const float4*>(Kc + (size_t)j*16);
    float4 k0=k4[0], k1=k4[1], k2=k4[2], k3=k4[3];
    const float4* v4 = reinterpret_cast<const float4*>(Vc + (size_t)j*16);
    float4 v0=v4[0], v1=v4[1], v2=v4[2], v3=v4[3];
    #pragma unroll
    for (int r = 0; r < 4; ++r){
      float s;
      DOT16(s, r, k0, k1, k2, k3);
      if (s > m[r]){
        float sc = __expf(m[r]-s);
        l[r] = fmaf(l[r], sc, 1.f);
        ACC_SCALE(r, sc, v0, v1, v2, v3);
        m[r] = s;
      } else {
        float pp = __expf(s - m[r]);
        l[r] += pp;
        ACC_ADD(r, pp, v0, v1, v2, v3);
      }
    }
  }
  // butterfly merge across all 64 lanes
  #pragma unroll
  for (int mask = 1; mask < 64; mask <<= 1){
    #pragma unroll
    for (int r = 0; r < 4; ++r){
      float mo = __shfl_xor(m[r], mask);
      float lo = __shfl_xor(l[r], mask);
      float mn = fmaxf(m[r], mo);
      float s1 = __expf(m[r]-mn), s2 = __expf(mo-mn);
      l[r] = l[r]*s1 + lo*s2;
      #pragma unroll
      for (int d = 0; d < 16; ++d){
        float ao = __shfl_xor(acc[r][d], mask);
        acc[r][d] = acc[r][d]*s1 + ao*s2;
      }
      m[r] = mn;
    }
  }
  // epilogue: lane (qi,c): softmax over 16 dims of query qi, channel c of W3
  const int qi = lane >> 4, c = lane & 15;
  float lq = (qi==0)?l[0]:(qi==1)?l[1]:(qi==2)?l[2]:l[3];
  float aq[16];
  #pragma unroll
  for (int d = 0; d < 16; ++d)
    aq[d] = (qi==0)?acc[0][d]:(qi==1)?acc[1][d]:(qi==2)?acc[2][d]:acc[3][d];
  float inv = 1.f/lq;
  float smax = -1e30f;
  #pragma unroll
  for (int d = 0; d < 16; ++d){ aq[d] *= inv; smax = fmaxf(smax, aq[d]); }
  float ssum = 0.f;
  #pragma unroll
  for (int d = 0; d < 16; ++d){ aq[d] = __expf(aq[d]-smax); ssum += aq[d]; }
  float sinv = 1.f/ssum;
  const float* W  = cm ? cm2W : cm1W;
  const float* Bb = cm ? cm2b : cm1b;
  float o = Bb[48 + c];
  #pragma unroll
  for (int d = 0; d < 16; ++d) o = fmaf(W[768 + c*16 + d], aq[d]*sinv, o);
  o = relu6f(o);
  ws[OFF_Y + (size_t)((cm ? 32 : 0) + c)*TT + (t0 + qi)] = o;
}

// ---------------- conv0: (1,48,4096) -> (5,24,4094), k=(2,3), s=(2,1)
__global__ __launch_bounds__(256) void k_conv0(const float* __restrict__ cw0,
    const float* __restrict__ cb, float* __restrict__ ws){
  const int idx = blockIdx.x*256 + threadIdx.x;
  const int WO = 4094, HO = 24;
  if (idx >= 5*HO*WO) return;
  const int ow = idx % WO; int tmp = idx / WO;
  const int oh = tmp % HO; const int oc = tmp / HO;
  const float* y = ws + OFF_Y;
  const float* w = cw0 + oc*6;
  float a = cb[oc];
  #pragma unroll
  for (int kh = 0; kh < 2; ++kh)
    #pragma unroll
    for (int kw = 0; kw < 3; ++kw)
      a = fmaf(w[kh*3+kw], y[(size_t)(2*oh+kh)*TT + ow + kw], a);
  ws[OFF_C0 + idx] = relu6f(a);
}

// ---------------- conv1: (5,24,4094) -> (5,12,1023), k=(2,4), s=(2,4)
__global__ __launch_bounds__(256) void k_conv1(const float* __restrict__ cw1,
    const float* __restrict__ cb, float* __restrict__ ws){
  const int idx = blockIdx.x*256 + threadIdx.x;
  const int WO = 1023, HO = 12, WI = 4094, HI = 24;
  if (idx >= 5*HO*WO) return;
  const int ow = idx % WO; int tmp = idx / WO;
  const int oh = tmp % HO; const int oc = tmp / HO;
  const float* c0 = ws + OFF_C0;
  float a = cb[5 + oc];
  #pragma unroll
  for (int ic = 0; ic < 5; ++ic)
    #pragma unroll
    for (int kh = 0; kh < 2; ++kh)
      #pragma unroll
      for (int kw = 0; kw < 4; ++kw)
        a = fmaf(cw1[((oc*5+ic)*2+kh)*4+kw], c0[(size_t)(ic*HI + 2*oh+kh)*WI + 4*ow+kw], a);
  ws[OFF_C1 + idx] = relu6f(a);
}

// ---------------- tail: conv2 -> conv3 -> fc1(sigmoid) -> fc2(softmax), one block
__global__ __launch_bounds__(256) void k_tail(const float* __restrict__ cw2,
    const float* __restrict__ cw3, const float* __restrict__ cb,
    const float* __restrict__ fc1W, const float* __restrict__ fc1b,
    const float* __restrict__ fc2W, const float* __restrict__ fc2b,
    const float* __restrict__ ws, float* __restrict__ out){
  __shared__ float c2[5*6*255];   // 30.6 KB
  __shared__ float c3[5*3*84];    // 5 KB
  const int tid = threadIdx.x;
  const float* c1 = ws + OFF_C1;  // (5,12,1023)
  // conv2: k=(2,4), s=(2,4) -> (5,6,255)
  for (int idx = tid; idx < 5*6*255; idx += 256){
    const int ow = idx % 255; int tmp = idx/255;
    const int oh = tmp % 6; const int oc = tmp/6;
    float a = cb[10 + oc];
    #pragma unroll
    for (int ic = 0; ic < 5; ++ic)
      #pragma unroll
      for (int kh = 0; kh < 2; ++kh)
        #pragma unroll
        for (int kw = 0; kw < 4; ++kw)
          a = fmaf(cw2[((oc*5+ic)*2+kh)*4+kw], c1[(size_t)(ic*12 + 2*oh+kh)*1023 + 4*ow+kw], a);
    c2[idx] = relu6f(a);
  }
  __syncthreads();
  // conv3: k=(2,4), s=(2,3) -> (5,3,84)
  for (int idx = tid; idx < 5*3*84; idx += 256){
    const int ow = idx % 84; int tmp = idx/84;
    const int oh = tmp % 3; const int oc = tmp/3;
    float a = cb[15 + oc];
    #pragma unroll
    for (int ic = 0; ic < 5; ++ic)
      #pragma unroll
      for (int kh = 0; kh < 2; ++kh)
        #pragma unroll
        for (int kw = 0; kw < 4; ++kw)
          a = fmaf(cw3[((oc*5+ic)*2+kh)*4+kw], c2[(ic*6 + 2*oh+kh)*255 + 3*ow+kw], a);
    c3[idx] = relu6f(a);
  }
  __syncthreads();
  // fc: (42,30) -> sigmoid(15) -> softmax(2)
  if (tid < 42){
    const float* row = c3 + tid*30;
    float h[15];
    #pragma unroll
    for (int kx = 0; kx < 15; ++kx){
      float a = fc1b[kx];
      for (int n = 0; n < 30; ++n) a = fmaf(fc1W[kx*30+n], row[n], a);
      h[kx] = 1.f/(1.f + __expf(-a));
    }
    float l0 = fc2b[0], l1 = fc2b[1];
    #pragma unroll
    for (int kx = 0; kx < 15; ++kx){
      l0 = fmaf(fc2W[kx],    h[kx], l0);
      l1 = fmaf(fc2W[15+kx], h[kx], l1);
    }
    float mx = fmaxf(l0, l1);
    float e0 = __expf(l0-mx), e1 = __expf(l1-mx);
    float s = e0 + e1;
    out[tid*2]   = e0/s;
    out[tid*2+1] = e1/s;
  }
}

extern "C" void kernel_launch(void* const* d_in, const int* in_sizes, int n_in,
                              void* d_out, int out_size, void* d_ws, size_t ws_size,
                              hipStream_t stream){
  const float* x    = (const float*)d_in[0];
  const float* cm1W = (const float*)d_in[1];
  const float* cm1b = (const float*)d_in[2];
  const float* cm2W = (const float*)d_in[3];
  const float* cm2b = (const float*)d_in[4];
  const float* cw0  = (const float*)d_in[5];
  const float* cw1  = (const float*)d_in[6];
  const float* cw2  = (const float*)d_in[7];
  const float* cw3  = (const float*)d_in[8];
  const float* cb   = (const float*)d_in[9];
  const float* fc1W = (const float*)d_in[10];
  const float* fc1b = (const float*)d_in[11];
  const float* fc2W = (const float*)d_in[12];
  const float* fc2b = (const float*)d_in[13];
  float* ws  = (float*)d_ws;
  float* out = (float*)d_out;

  k_gpart<<<dim3(32),  dim3(256), 0, stream>>>(x, ws);
  k_qkv  <<<dim3(32),  dim3(256), 0, stream>>>(x, cm1W, cm1b, cm2W, cm2b, ws);
  k_attn <<<dim3(512), dim3(256), 0, stream>>>(cm1W, cm1b, cm2W, cm2b, ws);
  k_conv0<<<dim3(1920),dim3(256), 0, stream>>>(cw0, cb, ws);
  k_conv1<<<dim3(240), dim3(256), 0, stream>>>(cw1, cb, ws);
  k_tail <<<dim3(1),   dim3(256), 0, stream>>>(cw2, cw3, cb, fc1W, fc1b, fc2W, fc2b, ws, out);
}

// Round 2
// 148.239 us; speedup vs baseline: 1.0047x; 1.0047x over previous
//
#include <hip/hip_runtime.h>

#define TT 4096
#define KSPLIT 16
#define KPB 256        // keys per block (KSPLIT * KPB = TT)
#define THR 30.0f

// ws float offsets (P region is 11.93 MB total requirement; C0/C1/C2 alias dead P)
#define OFF_GPART 0        // [64][2][256]
#define OFF_Q     32768    // [2][4096][16]
#define OFF_K     163840
#define OFF_V     294912
#define OFF_Y     425984   // [48][4096]
#define OFF_P     622592   // [2][16][18][4096]  (flash partials: m,l,acc16)
#define OFF_C0    622592   // alias (conv0 runs after merge)
#define OFF_C1    1113872
#define OFF_C2    1175252

__device__ __forceinline__ float relu6f(float v){ return fminf(fmaxf(v, 0.f), 6.f); }

// ---------------- G partials: G[i][j] = sum_t wav[t]*e_i[t]*e_j[t] ----------------
__global__ __launch_bounds__(256) void k_gpart(const float* __restrict__ x, float* __restrict__ ws){
  const int b = blockIdx.x, tid = threadIdx.x;        // 64 blocks x 64 t
  const int i = tid >> 4, j = tid & 15;
  const float* ei = x + (size_t)(1+i)*TT;
  const float* ej = x + (size_t)(1+j)*TT;
  const float* wA = x;
  const float* wB = x + (size_t)17*TT;
  float gA = 0.f, gB = 0.f;
  const int t0 = b*64;
  #pragma unroll 4
  for (int t = t0; t < t0+64; ++t){
    float p = ei[t]*ej[t];
    gA = fmaf(wA[t], p, gA);
    gB = fmaf(wB[t], p, gB);
  }
  ws[OFF_GPART + b*512 + tid]       = gA;
  ws[OFF_GPART + b*512 + 256 + tid] = gB;
}

// ---------------- QKV: w2 = G @ (wav*e); Q=relu6(W0 e+b0); K=relu6(W1 w2+b1); V=relu6(W2 w2+b2)
__global__ __launch_bounds__(128) void k_qkv(const float* __restrict__ x,
    const float* __restrict__ cm1W, const float* __restrict__ cm1b,
    const float* __restrict__ cm2W, const float* __restrict__ cm2b,
    float* __restrict__ ws){
  __shared__ float4 sG4[64];
  __shared__ float4 sW0[64], sW1[64], sW2[64];
  __shared__ float sB[48];
  const int b = blockIdx.x;           // 64 blocks: cm = b>>5
  const int cm = b >> 5;
  const int tid = threadIdx.x;        // 128 threads
  float g0 = 0.f, g1 = 0.f;
  for (int blk = 0; blk < 64; ++blk){
    g0 += ws[OFF_GPART + blk*512 + cm*256 + tid];
    g1 += ws[OFF_GPART + blk*512 + cm*256 + 128 + tid];
  }
  ((float*)sG4)[tid]       = g0;
  ((float*)sG4)[tid + 128] = g1;
  const float* W  = cm ? cm2W : cm1W;
  const float* Bb = cm ? cm2b : cm1b;
  ((float*)sW0)[tid]       = W[tid];
  ((float*)sW0)[tid + 128] = W[tid + 128];
  ((float*)sW1)[tid]       = W[256 + tid];
  ((float*)sW1)[tid + 128] = W[384 + tid];
  ((float*)sW2)[tid]       = W[512 + tid];
  ((float*)sW2)[tid + 128] = W[640 + tid];
  if (tid < 48) sB[tid] = Bb[tid];
  __syncthreads();

  const int t = (b & 31)*128 + tid;
  float e[16], p[16], w2[16];
  const float wav = x[(size_t)(cm ? 17 : 0)*TT + t];
  #pragma unroll
  for (int d = 0; d < 16; ++d){ e[d] = x[(size_t)(1+d)*TT + t]; p[d] = wav * e[d]; }

  #pragma unroll
  for (int c = 0; c < 16; ++c){
    float a = 0.f;
    #pragma unroll
    for (int dv = 0; dv < 4; ++dv){
      float4 gv = sG4[c*4+dv];
      a = fmaf(gv.x, p[4*dv+0], a); a = fmaf(gv.y, p[4*dv+1], a);
      a = fmaf(gv.z, p[4*dv+2], a); a = fmaf(gv.w, p[4*dv+3], a);
    }
    w2[c] = a;
  }
  float q[16], kk[16], vv[16];
  #pragma unroll
  for (int c = 0; c < 16; ++c){
    float aq = sB[c], ak = sB[16+c], av = sB[32+c];
    #pragma unroll
    for (int dv = 0; dv < 4; ++dv){
      float4 w0 = sW0[c*4+dv], w1 = sW1[c*4+dv], w3 = sW2[c*4+dv];
      aq = fmaf(w0.x, e[4*dv+0], aq);  aq = fmaf(w0.y, e[4*dv+1], aq);
      aq = fmaf(w0.z, e[4*dv+2], aq);  aq = fmaf(w0.w, e[4*dv+3], aq);
      ak = fmaf(w1.x, w2[4*dv+0], ak); ak = fmaf(w1.y, w2[4*dv+1], ak);
      ak = fmaf(w1.z, w2[4*dv+2], ak); ak = fmaf(w1.w, w2[4*dv+3], ak);
      av = fmaf(w3.x, w2[4*dv+0], av); av = fmaf(w3.y, w2[4*dv+1], av);
      av = fmaf(w3.z, w2[4*dv+2], av); av = fmaf(w3.w, w2[4*dv+3], av);
    }
    q[c] = relu6f(aq); kk[c] = relu6f(ak); vv[c] = relu6f(av);
  }
  float* Qp = ws + OFF_Q + ((size_t)cm*TT + t)*16;
  float* Kp = ws + OFF_K + ((size_t)cm*TT + t)*16;
  float* Vp = ws + OFF_V + ((size_t)cm*TT + t)*16;
  #pragma unroll
  for (int dv = 0; dv < 4; ++dv){
    reinterpret_cast<float4*>(Qp)[dv] = make_float4(q[4*dv],  q[4*dv+1],  q[4*dv+2],  q[4*dv+3]);
    reinterpret_cast<float4*>(Kp)[dv] = make_float4(kk[4*dv], kk[4*dv+1], kk[4*dv+2], kk[4*dv+3]);
    reinterpret_cast<float4*>(Vp)[dv] = make_float4(vv[4*dv], vv[4*dv+1], vv[4*dv+2], vv[4*dv+3]);
  }
  if (cm == 0){
    #pragma unroll
    for (int d = 0; d < 16; ++d) ws[OFF_Y + (size_t)(16+d)*TT + t] = e[d];
  }
}

// ---------------- attention main: query-per-lane, LDS-broadcast K/V, flash partials
__global__ __launch_bounds__(256) void k_attn_main(float* __restrict__ ws){
  __shared__ float sK[KPB*16];   // 16 KB
  __shared__ float sV[KPB*16];   // 16 KB
  const int b = blockIdx.x;           // 512 blocks: [cm][qblk 16][ks 16]
  const int cm = b >> 8;
  const int qblk = (b >> 4) & 15;
  const int ks = b & 15;
  const int tid = threadIdx.x;
  const int j0 = ks*KPB;

  // stage K/V slice (coalesced: one row per thread)
  {
    const float4* Ksrc = reinterpret_cast<const float4*>(ws + OFF_K + ((size_t)cm*TT + j0 + tid)*16);
    const float4* Vsrc = reinterpret_cast<const float4*>(ws + OFF_V + ((size_t)cm*TT + j0 + tid)*16);
    float4* Kd = reinterpret_cast<float4*>(sK + tid*16);
    float4* Vd = reinterpret_cast<float4*>(sV + tid*16);
    #pragma unroll
    for (int dv = 0; dv < 4; ++dv){ Kd[dv] = Ksrc[dv]; Vd[dv] = Vsrc[dv]; }
  }
  __syncthreads();

  const int q = qblk*256 + tid;       // this thread's query
  float qr[16];
  {
    const float4* q4 = reinterpret_cast<const float4*>(ws + OFF_Q + ((size_t)cm*TT + q)*16);
    float4 a = q4[0], bq = q4[1], c = q4[2], d = q4[3];
    qr[0]=a.x;  qr[1]=a.y;  qr[2]=a.z;  qr[3]=a.w;
    qr[4]=bq.x; qr[5]=bq.y; qr[6]=bq.z; qr[7]=bq.w;
    qr[8]=c.x;  qr[9]=c.y;  qr[10]=c.z; qr[11]=c.w;
    qr[12]=d.x; qr[13]=d.y; qr[14]=d.z; qr[15]=d.w;
  }
  float m = 0.f, l = 0.f, acc[16];
  #pragma unroll
  for (int d = 0; d < 16; ++d) acc[d] = 0.f;

  for (int k = 0; k < KPB; ++k){
    const float4* kp = reinterpret_cast<const float4*>(sK + k*16);
    float4 k0=kp[0], k1=kp[1], k2=kp[2], k3=kp[3];
    float s =        qr[0]*k0.x;
    s=fmaf(qr[1],k0.y,s);  s=fmaf(qr[2],k0.z,s);  s=fmaf(qr[3],k0.w,s);
    s=fmaf(qr[4],k1.x,s);  s=fmaf(qr[5],k1.y,s);  s=fmaf(qr[6],k1.z,s);  s=fmaf(qr[7],k1.w,s);
    s=fmaf(qr[8],k2.x,s);  s=fmaf(qr[9],k2.y,s);  s=fmaf(qr[10],k2.z,s); s=fmaf(qr[11],k2.w,s);
    s=fmaf(qr[12],k3.x,s); s=fmaf(qr[13],k3.y,s); s=fmaf(qr[14],k3.z,s); s=fmaf(qr[15],k3.w,s);
    if (__any(s > m + THR)){            // rare, wave-uniform
      float mn = fmaxf(m, s);
      float sc = __expf(m - mn);
      l *= sc;
      #pragma unroll
      for (int d = 0; d < 16; ++d) acc[d] *= sc;
      m = mn;
    }
    float p = __expf(s - m);
    l += p;
    const float4* vp = reinterpret_cast<const float4*>(sV + k*16);
    float4 v0=vp[0], v1=vp[1], v2=vp[2], v3=vp[3];
    acc[0]=fmaf(p,v0.x,acc[0]);  acc[1]=fmaf(p,v0.y,acc[1]);
    acc[2]=fmaf(p,v0.z,acc[2]);  acc[3]=fmaf(p,v0.w,acc[3]);
    acc[4]=fmaf(p,v1.x,acc[4]);  acc[5]=fmaf(p,v1.y,acc[5]);
    acc[6]=fmaf(p,v1.z,acc[6]);  acc[7]=fmaf(p,v1.w,acc[7]);
    acc[8]=fmaf(p,v2.x,acc[8]);  acc[9]=fmaf(p,v2.y,acc[9]);
    acc[10]=fmaf(p,v2.z,acc[10]); acc[11]=fmaf(p,v2.w,acc[11]);
    acc[12]=fmaf(p,v3.x,acc[12]); acc[13]=fmaf(p,v3.y,acc[13]);
    acc[14]=fmaf(p,v3.z,acc[14]); acc[15]=fmaf(p,v3.w,acc[15]);
  }
  // write partials [cm][ks][18][TT] (coalesced across lanes)
  float* Pb = ws + OFF_P + ((size_t)(cm*KSPLIT + ks)*18)*TT + q;
  Pb[0]  = m;
  Pb[TT] = l;
  #pragma unroll
  for (int d = 0; d < 16; ++d) Pb[(size_t)(2+d)*TT] = acc[d];
}

// ---------------- attention merge + softmax16 + W3 epilogue -> y rows
__global__ __launch_bounds__(64) void k_attn_merge(
    const float* __restrict__ cm1W, const float* __restrict__ cm1b,
    const float* __restrict__ cm2W, const float* __restrict__ cm2b,
    float* __restrict__ ws){
  const int gid = blockIdx.x*64 + threadIdx.x;   // 128 blocks x 64
  const int cm = gid >> 12;
  const int q = gid & 4095;
  const float* Pb = ws + OFF_P + (size_t)cm*KSPLIT*18*TT + q;
  float mks[KSPLIT], M = -1e30f;
  #pragma unroll
  for (int ks = 0; ks < KSPLIT; ++ks){ mks[ks] = Pb[(size_t)(ks*18)*TT]; M = fmaxf(M, mks[ks]); }
  float sc[KSPLIT], lt = 0.f;
  #pragma unroll
  for (int ks = 0; ks < KSPLIT; ++ks){
    sc[ks] = __expf(mks[ks] - M);
    lt = fmaf(Pb[(size_t)(ks*18+1)*TT], sc[ks], lt);
  }
  float a[16];
  #pragma unroll
  for (int d = 0; d < 16; ++d){
    float s = 0.f;
    #pragma unroll
    for (int ks = 0; ks < KSPLIT; ++ks) s = fmaf(Pb[(size_t)(ks*18+2+d)*TT], sc[ks], s);
    a[d] = s;
  }
  const float invl = 1.f/lt;
  float mx = -1e30f;
  #pragma unroll
  for (int d = 0; d < 16; ++d){ a[d] *= invl; mx = fmaxf(mx, a[d]); }
  float es = 0.f;
  #pragma unroll
  for (int d = 0; d < 16; ++d){ a[d] = __expf(a[d]-mx); es += a[d]; }
  const float invs = 1.f/es;
  const float* W  = cm ? cm2W : cm1W;
  const float* Bb = cm ? cm2b : cm1b;
  #pragma unroll
  for (int c = 0; c < 16; ++c){
    float o = 0.f;
    #pragma unroll
    for (int d = 0; d < 16; ++d) o = fmaf(W[768 + c*16 + d], a[d], o);
    o = relu6f(fmaf(o, invs, Bb[48 + c]));
    ws[OFF_Y + (size_t)((cm ? 32 : 0) + c)*TT + q] = o;
  }
}

// ---------------- conv0: (1,48,4096) -> (5,24,4094), k=(2,3), s=(2,1)
__global__ __launch_bounds__(256) void k_conv0(const float* __restrict__ cw0,
    const float* __restrict__ cb, float* __restrict__ ws){
  const int idx = blockIdx.x*256 + threadIdx.x;
  const int WO = 4094, HO = 24;
  if (idx >= 5*HO*WO) return;
  const int ow = idx % WO; int tmp = idx / WO;
  const int oh = tmp % HO; const int oc = tmp / HO;
  const float* y = ws + OFF_Y;
  const float* w = cw0 + oc*6;
  float a = cb[oc];
  #pragma unroll
  for (int kh = 0; kh < 2; ++kh)
    #pragma unroll
    for (int kw = 0; kw < 3; ++kw)
      a = fmaf(w[kh*3+kw], y[(size_t)(2*oh+kh)*TT + ow + kw], a);
  ws[OFF_C0 + idx] = relu6f(a);
}

// ---------------- conv1: (5,24,4094) -> (5,12,1023), k=(2,4), s=(2,4)
__global__ __launch_bounds__(256) void k_conv1(const float* __restrict__ cw1,
    const float* __restrict__ cb, float* __restrict__ ws){
  const int idx = blockIdx.x*256 + threadIdx.x;
  const int WO = 1023, HO = 12, WI = 4094, HI = 24;
  if (idx >= 5*HO*WO) return;
  const int ow = idx % WO; int tmp = idx / WO;
  const int oh = tmp % HO; const int oc = tmp / HO;
  const float* c0 = ws + OFF_C0;
  float a = cb[5 + oc];
  #pragma unroll
  for (int ic = 0; ic < 5; ++ic)
    #pragma unroll
    for (int kh = 0; kh < 2; ++kh)
      #pragma unroll
      for (int kw = 0; kw < 4; ++kw)
        a = fmaf(cw1[((oc*5+ic)*2+kh)*4+kw], c0[(size_t)(ic*HI + 2*oh+kh)*WI + 4*ow+kw], a);
  ws[OFF_C1 + idx] = relu6f(a);
}

// ---------------- conv2: (5,12,1023) -> (5,6,255), k=(2,4), s=(2,4)
__global__ __launch_bounds__(256) void k_conv2(const float* __restrict__ cw2,
    const float* __restrict__ cb, float* __restrict__ ws){
  const int idx = blockIdx.x*256 + threadIdx.x;
  if (idx >= 5*6*255) return;
  const int ow = idx % 255; int tmp = idx/255;
  const int oh = tmp % 6; const int oc = tmp/6;
  const float* c1 = ws + OFF_C1;
  float a = cb[10 + oc];
  #pragma unroll
  for (int ic = 0; ic < 5; ++ic)
    #pragma unroll
    for (int kh = 0; kh < 2; ++kh)
      #pragma unroll
      for (int kw = 0; kw < 4; ++kw)
        a = fmaf(cw2[((oc*5+ic)*2+kh)*4+kw], c1[(size_t)(ic*12 + 2*oh+kh)*1023 + 4*ow+kw], a);
  ws[OFF_C2 + idx] = relu6f(a);
}

// ---------------- tail: conv3 -> fc1(sigmoid) -> fc2(softmax), one block, LDS-staged
__global__ __launch_bounds__(256) void k_tail(
    const float* __restrict__ cw3, const float* __restrict__ cb,
    const float* __restrict__ fc1W, const float* __restrict__ fc1b,
    const float* __restrict__ fc2W, const float* __restrict__ fc2b,
    const float* __restrict__ ws, float* __restrict__ out){
  __shared__ float c2[5*6*255];   // 30.6 KB
  __shared__ float c3[5*3*84];    // 5 KB
  const int tid = threadIdx.x;
  for (int i = tid; i < 5*6*255; i += 256) c2[i] = ws[OFF_C2 + i];
  __syncthreads();
  // conv3: k=(2,4), s=(2,3) -> (5,3,84)
  for (int idx = tid; idx < 5*3*84; idx += 256){
    const int ow = idx % 84; int tmp = idx/84;
    const int oh = tmp % 3; const int oc = tmp/3;
    float a = cb[15 + oc];
    #pragma unroll
    for (int ic = 0; ic < 5; ++ic)
      #pragma unroll
      for (int kh = 0; kh < 2; ++kh)
        #pragma unroll
        for (int kw = 0; kw < 4; ++kw)
          a = fmaf(cw3[((oc*5+ic)*2+kh)*4+kw], c2[(ic*6 + 2*oh+kh)*255 + 3*ow+kw], a);
    c3[idx] = relu6f(a);
  }
  __syncthreads();
  if (tid < 42){
    const float* row = c3 + tid*30;
    float h[15];
    #pragma unroll
    for (int kx = 0; kx < 15; ++kx){
      float a = fc1b[kx];
      for (int n = 0; n < 30; ++n) a = fmaf(fc1W[kx*30+n], row[n], a);
      h[kx] = 1.f/(1.f + __expf(-a));
    }
    float l0 = fc2b[0], l1 = fc2b[1];
    #pragma unroll
    for (int kx = 0; kx < 15; ++kx){
      l0 = fmaf(fc2W[kx],    h[kx], l0);
      l1 = fmaf(fc2W[15+kx], h[kx], l1);
    }
    float mx = fmaxf(l0, l1);
    float e0 = __expf(l0-mx), e1 = __expf(l1-mx);
    float s = e0 + e1;
    out[tid*2]   = e0/s;
    out[tid*2+1] = e1/s;
  }
}

extern "C" void kernel_launch(void* const* d_in, const int* in_sizes, int n_in,
                              void* d_out, int out_size, void* d_ws, size_t ws_size,
                              hipStream_t stream){
  const float* x    = (const float*)d_in[0];
  const float* cm1W = (const float*)d_in[1];
  const float* cm1b = (const float*)d_in[2];
  const float* cm2W = (const float*)d_in[3];
  const float* cm2b = (const float*)d_in[4];
  const float* cw0  = (const float*)d_in[5];
  const float* cw1  = (const float*)d_in[6];
  const float* cw2  = (const float*)d_in[7];
  const float* cw3  = (const float*)d_in[8];
  const float* cb   = (const float*)d_in[9];
  const float* fc1W = (const float*)d_in[10];
  const float* fc1b = (const float*)d_in[11];
  const float* fc2W = (const float*)d_in[12];
  const float* fc2b = (const float*)d_in[13];
  float* ws  = (float*)d_ws;
  float* out = (float*)d_out;

  k_gpart     <<<dim3(64),  dim3(256), 0, stream>>>(x, ws);
  k_qkv       <<<dim3(64),  dim3(128), 0, stream>>>(x, cm1W, cm1b, cm2W, cm2b, ws);
  k_attn_main <<<dim3(512), dim3(256), 0, stream>>>(ws);
  k_attn_merge<<<dim3(128), dim3(64),  0, stream>>>(cm1W, cm1b, cm2W, cm2b, ws);
  k_conv0     <<<dim3(1920),dim3(256), 0, stream>>>(cw0, cb, ws);
  k_conv1     <<<dim3(240), dim3(256), 0, stream>>>(cw1, cb, ws);
  k_conv2     <<<dim3(30),  dim3(256), 0, stream>>>(cw2, cb, ws);
  k_tail      <<<dim3(1),   dim3(256), 0, stream>>>(cw3, cb, fc1W, fc1b, fc2W, fc2b, ws, out);
}

// Round 3
// 95.482 us; speedup vs baseline: 1.5598x; 1.5525x over previous
//
#include <hip/hip_runtime.h>

#define TT 4096
#define KSPLIT 16
#define KPB 256        // keys per block slice

// ws float offsets (total 2,850,816 floats = 11.4 MB; within proven envelope)
#define OFF_GPART 0        // [64][2][256]
#define OFF_Q     32768    // [2][4096][16]
#define OFF_K     163840
#define OFF_V     294912
#define OFF_Y     425984   // [48][4096]
#define OFF_P     622592   // [2][16][17][4096] flash partials (l, acc0..15), fixed-shift
// merged M aliases the ks=0 plane of P: M[cm][d][q] = P + (cm*16*17 + d)*TT + q
#define OFF_C0    622592   // alias (conv0 runs after attn_epi)
#define OFF_C1    1113872
#define OFF_C2    1175252

__device__ __forceinline__ float relu6f(float v){ return fminf(fmaxf(v, 0.f), 6.f); }

// ---------------- G partials: G[i][j] = sum_t wav[t]*e_i[t]*e_j[t] ----------------
__global__ __launch_bounds__(256) void k_gpart(const float* __restrict__ x, float* __restrict__ ws){
  const int b = blockIdx.x, tid = threadIdx.x;        // 64 blocks x 64 t
  const int i = tid >> 4, j = tid & 15;
  const float* ei = x + (size_t)(1+i)*TT;
  const float* ej = x + (size_t)(1+j)*TT;
  const float* wA = x;
  const float* wB = x + (size_t)17*TT;
  float gA = 0.f, gB = 0.f;
  const int t0 = b*64;
  #pragma unroll 4
  for (int t = t0; t < t0+64; ++t){
    float p = ei[t]*ej[t];
    gA = fmaf(wA[t], p, gA);
    gB = fmaf(wB[t], p, gB);
  }
  ws[OFF_GPART + b*512 + tid]       = gA;
  ws[OFF_GPART + b*512 + 256 + tid] = gB;
}

// ---------------- QKV: w2 = G @ (wav*e); Q=relu6(W0 e+b0); K=relu6(W1 w2+b1); V=relu6(W2 w2+b2)
__global__ __launch_bounds__(128) void k_qkv(const float* __restrict__ x,
    const float* __restrict__ cm1W, const float* __restrict__ cm1b,
    const float* __restrict__ cm2W, const float* __restrict__ cm2b,
    float* __restrict__ ws){
  __shared__ float4 sG4[64];
  __shared__ float4 sW0[64], sW1[64], sW2[64];
  __shared__ float sB[48];
  const int b = blockIdx.x;           // 64 blocks: cm = b>>5
  const int cm = b >> 5;
  const int tid = threadIdx.x;        // 128 threads
  float g0 = 0.f, g1 = 0.f;
  for (int blk = 0; blk < 64; ++blk){
    g0 += ws[OFF_GPART + blk*512 + cm*256 + tid];
    g1 += ws[OFF_GPART + blk*512 + cm*256 + 128 + tid];
  }
  ((float*)sG4)[tid]       = g0;
  ((float*)sG4)[tid + 128] = g1;
  const float* W  = cm ? cm2W : cm1W;
  const float* Bb = cm ? cm2b : cm1b;
  ((float*)sW0)[tid]       = W[tid];
  ((float*)sW0)[tid + 128] = W[tid + 128];
  ((float*)sW1)[tid]       = W[256 + tid];
  ((float*)sW1)[tid + 128] = W[384 + tid];
  ((float*)sW2)[tid]       = W[512 + tid];
  ((float*)sW2)[tid + 128] = W[640 + tid];
  if (tid < 48) sB[tid] = Bb[tid];
  __syncthreads();

  const int t = (b & 31)*128 + tid;
  float e[16], p[16], w2[16];
  const float wav = x[(size_t)(cm ? 17 : 0)*TT + t];
  #pragma unroll
  for (int d = 0; d < 16; ++d){ e[d] = x[(size_t)(1+d)*TT + t]; p[d] = wav * e[d]; }

  #pragma unroll
  for (int c = 0; c < 16; ++c){
    float a = 0.f;
    #pragma unroll
    for (int dv = 0; dv < 4; ++dv){
      float4 gv = sG4[c*4+dv];
      a = fmaf(gv.x, p[4*dv+0], a); a = fmaf(gv.y, p[4*dv+1], a);
      a = fmaf(gv.z, p[4*dv+2], a); a = fmaf(gv.w, p[4*dv+3], a);
    }
    w2[c] = a;
  }
  float q[16], kk[16], vv[16];
  #pragma unroll
  for (int c = 0; c < 16; ++c){
    float aq = sB[c], ak = sB[16+c], av = sB[32+c];
    #pragma unroll
    for (int dv = 0; dv < 4; ++dv){
      float4 w0 = sW0[c*4+dv], w1 = sW1[c*4+dv], w3 = sW2[c*4+dv];
      aq = fmaf(w0.x, e[4*dv+0], aq);  aq = fmaf(w0.y, e[4*dv+1], aq);
      aq = fmaf(w0.z, e[4*dv+2], aq);  aq = fmaf(w0.w, e[4*dv+3], aq);
      ak = fmaf(w1.x, w2[4*dv+0], ak); ak = fmaf(w1.y, w2[4*dv+1], ak);
      ak = fmaf(w1.z, w2[4*dv+2], ak); ak = fmaf(w1.w, w2[4*dv+3], ak);
      av = fmaf(w3.x, w2[4*dv+0], av); av = fmaf(w3.y, w2[4*dv+1], av);
      av = fmaf(w3.z, w2[4*dv+2], av); av = fmaf(w3.w, w2[4*dv+3], av);
    }
    q[c] = relu6f(aq); kk[c] = relu6f(ak); vv[c] = relu6f(av);
  }
  float* Qp = ws + OFF_Q + ((size_t)cm*TT + t)*16;
  float* Kp = ws + OFF_K + ((size_t)cm*TT + t)*16;
  float* Vp = ws + OFF_V + ((size_t)cm*TT + t)*16;
  #pragma unroll
  for (int dv = 0; dv < 4; ++dv){
    reinterpret_cast<float4*>(Qp)[dv] = make_float4(q[4*dv],  q[4*dv+1],  q[4*dv+2],  q[4*dv+3]);
    reinterpret_cast<float4*>(Kp)[dv] = make_float4(kk[4*dv], kk[4*dv+1], kk[4*dv+2], kk[4*dv+3]);
    reinterpret_cast<float4*>(Vp)[dv] = make_float4(vv[4*dv], vv[4*dv+1], vv[4*dv+2], vv[4*dv+3]);
  }
  if (cm == 0){
    #pragma unroll
    for (int d = 0; d < 16; ++d) ws[OFF_Y + (size_t)(16+d)*TT + t] = e[d];
  }
}

// ---------------- attention main: query-per-lane, uniform (scalar) K/V reads,
// fixed-shift softmax -> linear partials [cm][ks][17][TT]
__global__ __launch_bounds__(256) void k_attn_main(float* __restrict__ ws){
  const int b = blockIdx.x;           // 512 blocks: [cm][qblk 16][ks 16]
  const int cm = b >> 8;
  const int qblk = (b >> 4) & 15;
  const int ks = b & 15;
  const int tid = threadIdx.x;
  const int j0 = ks*KPB;
  const float* Kc = ws + OFF_K + ((size_t)cm*TT + j0)*16;
  const float* Vc = ws + OFF_V + ((size_t)cm*TT + j0)*16;

  const int q = qblk*256 + tid;
  float qr[16];
  {
    const float4* q4 = reinterpret_cast<const float4*>(ws + OFF_Q + ((size_t)cm*TT + q)*16);
    float4 a = q4[0], bq = q4[1], c = q4[2], d = q4[3];
    qr[0]=a.x;  qr[1]=a.y;  qr[2]=a.z;  qr[3]=a.w;
    qr[4]=bq.x; qr[5]=bq.y; qr[6]=bq.z; qr[7]=bq.w;
    qr[8]=c.x;  qr[9]=c.y;  qr[10]=c.z; qr[11]=c.w;
    qr[12]=d.x; qr[13]=d.y; qr[14]=d.z; qr[15]=d.w;
  }
  float l = 0.f, acc[16];
  #pragma unroll
  for (int d = 0; d < 16; ++d) acc[d] = 0.f;

  #pragma unroll 2
  for (int k = 0; k < KPB; ++k){
    // block-uniform addresses -> scalar loads / L1 broadcast
    const float4* kp = reinterpret_cast<const float4*>(Kc + k*16);
    float4 k0=kp[0], k1=kp[1], k2=kp[2], k3=kp[3];
    float s =        qr[0]*k0.x;
    s=fmaf(qr[1],k0.y,s);  s=fmaf(qr[2],k0.z,s);  s=fmaf(qr[3],k0.w,s);
    s=fmaf(qr[4],k1.x,s);  s=fmaf(qr[5],k1.y,s);  s=fmaf(qr[6],k1.z,s);  s=fmaf(qr[7],k1.w,s);
    s=fmaf(qr[8],k2.x,s);  s=fmaf(qr[9],k2.y,s);  s=fmaf(qr[10],k2.z,s); s=fmaf(qr[11],k2.w,s);
    s=fmaf(qr[12],k3.x,s); s=fmaf(qr[13],k3.y,s); s=fmaf(qr[14],k3.z,s); s=fmaf(qr[15],k3.w,s);
    s = fminf(s, 100.f);                 // overflow guard (p <= e^68)
    float p = __expf(s - 32.f);          // fixed shift -> linear partials
    l += p;
    const float4* vp = reinterpret_cast<const float4*>(Vc + k*16);
    float4 v0=vp[0], v1=vp[1], v2=vp[2], v3=vp[3];
    acc[0]=fmaf(p,v0.x,acc[0]);  acc[1]=fmaf(p,v0.y,acc[1]);
    acc[2]=fmaf(p,v0.z,acc[2]);  acc[3]=fmaf(p,v0.w,acc[3]);
    acc[4]=fmaf(p,v1.x,acc[4]);  acc[5]=fmaf(p,v1.y,acc[5]);
    acc[6]=fmaf(p,v1.z,acc[6]);  acc[7]=fmaf(p,v1.w,acc[7]);
    acc[8]=fmaf(p,v2.x,acc[8]);  acc[9]=fmaf(p,v2.y,acc[9]);
    acc[10]=fmaf(p,v2.z,acc[10]); acc[11]=fmaf(p,v2.w,acc[11]);
    acc[12]=fmaf(p,v3.x,acc[12]); acc[13]=fmaf(p,v3.y,acc[13]);
    acc[14]=fmaf(p,v3.z,acc[14]); acc[15]=fmaf(p,v3.w,acc[15]);
  }
  float* Pb = ws + OFF_P + (size_t)((cm*KSPLIT + ks)*17)*TT + q;
  Pb[0] = l;
  #pragma unroll
  for (int d = 0; d < 16; ++d) Pb[(size_t)(1+d)*TT] = acc[d];
}

// ---------------- sum partials over ks (linear merge); result aliases ks=0 plane
__global__ __launch_bounds__(256) void k_attn_sum(float* __restrict__ ws){
  const int idx = blockIdx.x*256 + threadIdx.x;   // 544 blocks
  if (idx >= 2*17*TT) return;
  const int cm = idx / (17*TT);
  const int r  = idx - cm*17*TT;                  // d*TT + q
  const float* Pb = ws + OFF_P + (size_t)cm*KSPLIT*17*TT + r;
  float s = 0.f;
  #pragma unroll
  for (int ks = 0; ks < KSPLIT; ++ks) s += Pb[(size_t)ks*17*TT];
  ws[OFF_P + (size_t)cm*KSPLIT*17*TT + r] = s;    // write ks=0 plane (read-before-write per thread)
}

// ---------------- epilogue: /l, softmax16, W3 -> y rows
__global__ __launch_bounds__(128) void k_attn_epi(
    const float* __restrict__ cm1W, const float* __restrict__ cm1b,
    const float* __restrict__ cm2W, const float* __restrict__ cm2b,
    float* __restrict__ ws){
  const int gid = blockIdx.x*128 + threadIdx.x;   // 64 blocks x 128
  const int cm = gid >> 12;
  const int q = gid & 4095;
  const float* Mb = ws + OFF_P + (size_t)cm*KSPLIT*17*TT + q;
  const float lt = Mb[0];
  float a[16];
  #pragma unroll
  for (int d = 0; d < 16; ++d) a[d] = Mb[(size_t)(1+d)*TT];
  const float invl = 1.f/lt;
  float mx = -1e30f;
  #pragma unroll
  for (int d = 0; d < 16; ++d){ a[d] *= invl; mx = fmaxf(mx, a[d]); }
  float es = 0.f;
  #pragma unroll
  for (int d = 0; d < 16; ++d){ a[d] = __expf(a[d]-mx); es += a[d]; }
  const float invs = 1.f/es;
  const float* W  = cm ? cm2W : cm1W;
  const float* Bb = cm ? cm2b : cm1b;
  #pragma unroll
  for (int c = 0; c < 16; ++c){
    float o = 0.f;
    #pragma unroll
    for (int d = 0; d < 16; ++d) o = fmaf(W[768 + c*16 + d], a[d], o);
    o = relu6f(fmaf(o, invs, Bb[48 + c]));
    ws[OFF_Y + (size_t)((cm ? 32 : 0) + c)*TT + q] = o;
  }
}

// ---------------- conv0: (1,48,4096) -> (5,24,4094), k=(2,3), s=(2,1)
__global__ __launch_bounds__(256) void k_conv0(const float* __restrict__ cw0,
    const float* __restrict__ cb, float* __restrict__ ws){
  const int idx = blockIdx.x*256 + threadIdx.x;
  const int WO = 4094, HO = 24;
  if (idx >= 5*HO*WO) return;
  const int ow = idx % WO; int tmp = idx / WO;
  const int oh = tmp % HO; const int oc = tmp / HO;
  const float* y = ws + OFF_Y;
  const float* w = cw0 + oc*6;
  float a = cb[oc];
  #pragma unroll
  for (int kh = 0; kh < 2; ++kh)
    #pragma unroll
    for (int kw = 0; kw < 3; ++kw)
      a = fmaf(w[kh*3+kw], y[(size_t)(2*oh+kh)*TT + ow + kw], a);
  ws[OFF_C0 + idx] = relu6f(a);
}

// ---------------- conv1: (5,24,4094) -> (5,12,1023), k=(2,4), s=(2,4)
__global__ __launch_bounds__(256) void k_conv1(const float* __restrict__ cw1,
    const float* __restrict__ cb, float* __restrict__ ws){
  const int idx = blockIdx.x*256 + threadIdx.x;
  const int WO = 1023, HO = 12, WI = 4094, HI = 24;
  if (idx >= 5*HO*WO) return;
  const int ow = idx % WO; int tmp = idx / WO;
  const int oh = tmp % HO; const int oc = tmp / HO;
  const float* c0 = ws + OFF_C0;
  float a = cb[5 + oc];
  #pragma unroll
  for (int ic = 0; ic < 5; ++ic)
    #pragma unroll
    for (int kh = 0; kh < 2; ++kh)
      #pragma unroll
      for (int kw = 0; kw < 4; ++kw)
        a = fmaf(cw1[((oc*5+ic)*2+kh)*4+kw], c0[(size_t)(ic*HI + 2*oh+kh)*WI + 4*ow+kw], a);
  ws[OFF_C1 + idx] = relu6f(a);
}

// ---------------- conv2: (5,12,1023) -> (5,6,255), k=(2,4), s=(2,4)
__global__ __launch_bounds__(256) void k_conv2(const float* __restrict__ cw2,
    const float* __restrict__ cb, float* __restrict__ ws){
  const int idx = blockIdx.x*256 + threadIdx.x;
  if (idx >= 5*6*255) return;
  const int ow = idx % 255; int tmp = idx/255;
  const int oh = tmp % 6; const int oc = tmp/6;
  const float* c1 = ws + OFF_C1;
  float a = cb[10 + oc];
  #pragma unroll
  for (int ic = 0; ic < 5; ++ic)
    #pragma unroll
    for (int kh = 0; kh < 2; ++kh)
      #pragma unroll
      for (int kw = 0; kw < 4; ++kw)
        a = fmaf(cw2[((oc*5+ic)*2+kh)*4+kw], c1[(size_t)(ic*12 + 2*oh+kh)*1023 + 4*ow+kw], a);
  ws[OFF_C2 + idx] = relu6f(a);
}

// ---------------- tail: conv3 -> fc1(sigmoid) -> fc2(softmax), one block, LDS-staged
__global__ __launch_bounds__(256) void k_tail(
    const float* __restrict__ cw3, const float* __restrict__ cb,
    const float* __restrict__ fc1W, const float* __restrict__ fc1b,
    const float* __restrict__ fc2W, const float* __restrict__ fc2b,
    const float* __restrict__ ws, float* __restrict__ out){
  __shared__ float c2[5*6*255];   // 30.6 KB
  __shared__ float c3[5*3*84];    // 5 KB
  const int tid = threadIdx.x;
  for (int i = tid; i < 5*6*255; i += 256) c2[i] = ws[OFF_C2 + i];
  __syncthreads();
  // conv3: k=(2,4), s=(2,3) -> (5,3,84)
  for (int idx = tid; idx < 5*3*84; idx += 256){
    const int ow = idx % 84; int tmp = idx/84;
    const int oh = tmp % 3; const int oc = tmp/3;
    float a = cb[15 + oc];
    #pragma unroll
    for (int ic = 0; ic < 5; ++ic)
      #pragma unroll
      for (int kh = 0; kh < 2; ++kh)
        #pragma unroll
        for (int kw = 0; kw < 4; ++kw)
          a = fmaf(cw3[((oc*5+ic)*2+kh)*4+kw], c2[(ic*6 + 2*oh+kh)*255 + 3*ow+kw], a);
    c3[idx] = relu6f(a);
  }
  __syncthreads();
  if (tid < 42){
    const float* row = c3 + tid*30;
    float h[15];
    #pragma unroll
    for (int kx = 0; kx < 15; ++kx){
      float a = fc1b[kx];
      for (int n = 0; n < 30; ++n) a = fmaf(fc1W[kx*30+n], row[n], a);
      h[kx] = 1.f/(1.f + __expf(-a));
    }
    float l0 = fc2b[0], l1 = fc2b[1];
    #pragma unroll
    for (int kx = 0; kx < 15; ++kx){
      l0 = fmaf(fc2W[kx],    h[kx], l0);
      l1 = fmaf(fc2W[15+kx], h[kx], l1);
    }
    float mx = fmaxf(l0, l1);
    float e0 = __expf(l0-mx), e1 = __expf(l1-mx);
    float s = e0 + e1;
    out[tid*2]   = e0/s;
    out[tid*2+1] = e1/s;
  }
}

extern "C" void kernel_launch(void* const* d_in, const int* in_sizes, int n_in,
                              void* d_out, int out_size, void* d_ws, size_t ws_size,
                              hipStream_t stream){
  const float* x    = (const float*)d_in[0];
  const float* cm1W = (const float*)d_in[1];
  const float* cm1b = (const float*)d_in[2];
  const float* cm2W = (const float*)d_in[3];
  const float* cm2b = (const float*)d_in[4];
  const float* cw0  = (const float*)d_in[5];
  const float* cw1  = (const float*)d_in[6];
  const float* cw2  = (const float*)d_in[7];
  const float* cw3  = (const float*)d_in[8];
  const float* cb   = (const float*)d_in[9];
  const float* fc1W = (const float*)d_in[10];
  const float* fc1b = (const float*)d_in[11];
  const float* fc2W = (const float*)d_in[12];
  const float* fc2b = (const float*)d_in[13];
  float* ws  = (float*)d_ws;
  float* out = (float*)d_out;

  k_gpart    <<<dim3(64),  dim3(256), 0, stream>>>(x, ws);
  k_qkv      <<<dim3(64),  dim3(128), 0, stream>>>(x, cm1W, cm1b, cm2W, cm2b, ws);
  k_attn_main<<<dim3(512), dim3(256), 0, stream>>>(ws);
  k_attn_sum <<<dim3(544), dim3(256), 0, stream>>>(ws);
  k_attn_epi <<<dim3(64),  dim3(128), 0, stream>>>(cm1W, cm1b, cm2W, cm2b, ws);
  k_conv0    <<<dim3(1920),dim3(256), 0, stream>>>(cw0, cb, ws);
  k_conv1    <<<dim3(240), dim3(256), 0, stream>>>(cw1, cb, ws);
  k_conv2    <<<dim3(30),  dim3(256), 0, stream>>>(cw2, cb, ws);
  k_tail     <<<dim3(1),   dim3(256), 0, stream>>>(cw3, cb, fc1W, fc1b, fc2W, fc2b, ws, out);
}

// Round 4
// 81.985 us; speedup vs baseline: 1.8166x; 1.1646x over previous
//
#include <hip/hip_runtime.h>

#define TT 4096

// ws float offsets. KS=32 path needs P = 2*32*17*4096 floats -> end 5,079,040 floats (19.4 MiB).
// KS=16 path needs end 3,407,872 floats (13 MiB). Chosen at launch from ws_size (capture-time constant).
#define OFF_GPART 0        // [2][256][64] transposed partials
#define OFF_Q     32768    // [2][4096][16]
#define OFF_K     163840
#define OFF_V     294912
#define OFF_Y     425984   // [48][4096]
#define OFF_P     622592   // [2][KS][17][4096] flash partials (l, acc0..15), fixed-shift
#define OFF_C0    622592   // alias (conv stage runs after attn complete)
#define OFF_C1    1113872
#define OFF_C2    1175252

__device__ __forceinline__ float relu6f(float v){ return fminf(fmaxf(v, 0.f), 6.f); }

// ---------------- G partials (transposed): GPART[cm][ij][blk] ----------------
__global__ __launch_bounds__(256) void k_gpart(const float* __restrict__ x, float* __restrict__ ws){
  const int b = blockIdx.x, tid = threadIdx.x;        // 64 blocks x 64 t
  const int i = tid >> 4, j = tid & 15;
  const int t0 = b*64;
  const float4* ei4 = reinterpret_cast<const float4*>(x + (size_t)(1+i)*TT + t0);
  const float4* ej4 = reinterpret_cast<const float4*>(x + (size_t)(1+j)*TT + t0);
  const float4* wA4 = reinterpret_cast<const float4*>(x + t0);
  const float4* wB4 = reinterpret_cast<const float4*>(x + (size_t)17*TT + t0);
  float gA = 0.f, gB = 0.f;
  #pragma unroll 4
  for (int u = 0; u < 16; ++u){
    float4 a = ei4[u], c = ej4[u], wa = wA4[u], wb = wB4[u];
    float p0 = a.x*c.x, p1 = a.y*c.y, p2 = a.z*c.z, p3 = a.w*c.w;
    gA = fmaf(wa.x, p0, gA); gA = fmaf(wa.y, p1, gA); gA = fmaf(wa.z, p2, gA); gA = fmaf(wa.w, p3, gA);
    gB = fmaf(wb.x, p0, gB); gB = fmaf(wb.y, p1, gB); gB = fmaf(wb.z, p2, gB); gB = fmaf(wb.w, p3, gB);
  }
  ws[OFF_GPART + (size_t)tid*64 + b]         = gA;   // cm=0
  ws[OFF_GPART + (size_t)(256+tid)*64 + b]   = gB;   // cm=1
}

// ---------------- QKV ----------------
__global__ __launch_bounds__(128) void k_qkv(const float* __restrict__ x,
    const float* __restrict__ cm1W, const float* __restrict__ cm1b,
    const float* __restrict__ cm2W, const float* __restrict__ cm2b,
    float* __restrict__ ws){
  __shared__ float4 sG4[64];
  __shared__ float4 sW0[64], sW1[64], sW2[64];
  __shared__ float sB[48];
  const int b = blockIdx.x;           // 64 blocks: cm = b>>5
  const int cm = b >> 5;
  const int tid = threadIdx.x;        // 128 threads
  {
    const float4* g4a = reinterpret_cast<const float4*>(ws + OFF_GPART + (size_t)(cm*256 + tid)*64);
    const float4* g4b = reinterpret_cast<const float4*>(ws + OFF_GPART + (size_t)(cm*256 + 128 + tid)*64);
    float g0 = 0.f, g1 = 0.f;
    #pragma unroll
    for (int u = 0; u < 16; ++u){
      float4 a = g4a[u], c = g4b[u];
      g0 += (a.x + a.y) + (a.z + a.w);
      g1 += (c.x + c.y) + (c.z + c.w);
    }
    ((float*)sG4)[tid]       = g0;
    ((float*)sG4)[tid + 128] = g1;
  }
  const float* W  = cm ? cm2W : cm1W;
  const float* Bb = cm ? cm2b : cm1b;
  ((float*)sW0)[tid]       = W[tid];
  ((float*)sW0)[tid + 128] = W[tid + 128];
  ((float*)sW1)[tid]       = W[256 + tid];
  ((float*)sW1)[tid + 128] = W[384 + tid];
  ((float*)sW2)[tid]       = W[512 + tid];
  ((float*)sW2)[tid + 128] = W[640 + tid];
  if (tid < 48) sB[tid] = Bb[tid];
  __syncthreads();

  const int t = (b & 31)*128 + tid;
  float e[16], p[16], w2[16];
  const float wav = x[(size_t)(cm ? 17 : 0)*TT + t];
  #pragma unroll
  for (int d = 0; d < 16; ++d){ e[d] = x[(size_t)(1+d)*TT + t]; p[d] = wav * e[d]; }

  #pragma unroll
  for (int c = 0; c < 16; ++c){
    float a = 0.f;
    #pragma unroll
    for (int dv = 0; dv < 4; ++dv){
      float4 gv = sG4[c*4+dv];
      a = fmaf(gv.x, p[4*dv+0], a); a = fmaf(gv.y, p[4*dv+1], a);
      a = fmaf(gv.z, p[4*dv+2], a); a = fmaf(gv.w, p[4*dv+3], a);
    }
    w2[c] = a;
  }
  float q[16], kk[16], vv[16];
  #pragma unroll
  for (int c = 0; c < 16; ++c){
    float aq = sB[c], ak = sB[16+c], av = sB[32+c];
    #pragma unroll
    for (int dv = 0; dv < 4; ++dv){
      float4 w0 = sW0[c*4+dv], w1 = sW1[c*4+dv], w3 = sW2[c*4+dv];
      aq = fmaf(w0.x, e[4*dv+0], aq);  aq = fmaf(w0.y, e[4*dv+1], aq);
      aq = fmaf(w0.z, e[4*dv+2], aq);  aq = fmaf(w0.w, e[4*dv+3], aq);
      ak = fmaf(w1.x, w2[4*dv+0], ak); ak = fmaf(w1.y, w2[4*dv+1], ak);
      ak = fmaf(w1.z, w2[4*dv+2], ak); ak = fmaf(w1.w, w2[4*dv+3], ak);
      av = fmaf(w3.x, w2[4*dv+0], av); av = fmaf(w3.y, w2[4*dv+1], av);
      av = fmaf(w3.z, w2[4*dv+2], av); av = fmaf(w3.w, w2[4*dv+3], av);
    }
    q[c] = relu6f(aq); kk[c] = relu6f(ak); vv[c] = relu6f(av);
  }
  float* Qp = ws + OFF_Q + ((size_t)cm*TT + t)*16;
  float* Kp = ws + OFF_K + ((size_t)cm*TT + t)*16;
  float* Vp = ws + OFF_V + ((size_t)cm*TT + t)*16;
  #pragma unroll
  for (int dv = 0; dv < 4; ++dv){
    reinterpret_cast<float4*>(Qp)[dv] = make_float4(q[4*dv],  q[4*dv+1],  q[4*dv+2],  q[4*dv+3]);
    reinterpret_cast<float4*>(Kp)[dv] = make_float4(kk[4*dv], kk[4*dv+1], kk[4*dv+2], kk[4*dv+3]);
    reinterpret_cast<float4*>(Vp)[dv] = make_float4(vv[4*dv], vv[4*dv+1], vv[4*dv+2], vv[4*dv+3]);
  }
  if (cm == 0){
    #pragma unroll
    for (int d = 0; d < 16; ++d) ws[OFF_Y + (size_t)(16+d)*TT + t] = e[d];
  }
}

// ---------------- attention main (templated key-split) ----------------
template<int KS>
__global__ __launch_bounds__(256) void k_attn_main(float* __restrict__ ws){
  const int KPB = TT/KS;
  const int b = blockIdx.x;           // [cm][qblk 16][ks KS]
  const int cm = b / (16*KS);
  const int rem = b % (16*KS);
  const int qblk = rem / KS;
  const int ks = rem % KS;
  const int tid = threadIdx.x;
  const int j0 = ks*KPB;
  const float4* Kc4 = reinterpret_cast<const float4*>(ws + OFF_K + ((size_t)cm*TT + j0)*16);
  const float4* Vc4 = reinterpret_cast<const float4*>(ws + OFF_V + ((size_t)cm*TT + j0)*16);

  const int q = qblk*256 + tid;
  float qr[16];
  {
    const float4* q4 = reinterpret_cast<const float4*>(ws + OFF_Q + ((size_t)cm*TT + q)*16);
    float4 a = q4[0], bq = q4[1], c = q4[2], d = q4[3];
    qr[0]=a.x;  qr[1]=a.y;  qr[2]=a.z;  qr[3]=a.w;
    qr[4]=bq.x; qr[5]=bq.y; qr[6]=bq.z; qr[7]=bq.w;
    qr[8]=c.x;  qr[9]=c.y;  qr[10]=c.z; qr[11]=c.w;
    qr[12]=d.x; qr[13]=d.y; qr[14]=d.z; qr[15]=d.w;
  }
  float l = 0.f, acc[16];
  #pragma unroll
  for (int d = 0; d < 16; ++d) acc[d] = 0.f;

  #pragma unroll 4
  for (int k = 0; k < KPB; ++k){
    // block-uniform addresses -> scalar loads
    float4 k0=Kc4[4*k], k1=Kc4[4*k+1], k2=Kc4[4*k+2], k3=Kc4[4*k+3];
    float s =        qr[0]*k0.x;
    s=fmaf(qr[1],k0.y,s);  s=fmaf(qr[2],k0.z,s);  s=fmaf(qr[3],k0.w,s);
    s=fmaf(qr[4],k1.x,s);  s=fmaf(qr[5],k1.y,s);  s=fmaf(qr[6],k1.z,s);  s=fmaf(qr[7],k1.w,s);
    s=fmaf(qr[8],k2.x,s);  s=fmaf(qr[9],k2.y,s);  s=fmaf(qr[10],k2.z,s); s=fmaf(qr[11],k2.w,s);
    s=fmaf(qr[12],k3.x,s); s=fmaf(qr[13],k3.y,s); s=fmaf(qr[14],k3.z,s); s=fmaf(qr[15],k3.w,s);
    s = fminf(s, 100.f);                 // overflow guard
    float p = __expf(s - 32.f);          // fixed shift -> linear partials
    l += p;
    float4 v0=Vc4[4*k], v1=Vc4[4*k+1], v2=Vc4[4*k+2], v3=Vc4[4*k+3];
    acc[0]=fmaf(p,v0.x,acc[0]);  acc[1]=fmaf(p,v0.y,acc[1]);
    acc[2]=fmaf(p,v0.z,acc[2]);  acc[3]=fmaf(p,v0.w,acc[3]);
    acc[4]=fmaf(p,v1.x,acc[4]);  acc[5]=fmaf(p,v1.y,acc[5]);
    acc[6]=fmaf(p,v1.z,acc[6]);  acc[7]=fmaf(p,v1.w,acc[7]);
    acc[8]=fmaf(p,v2.x,acc[8]);  acc[9]=fmaf(p,v2.y,acc[9]);
    acc[10]=fmaf(p,v2.z,acc[10]); acc[11]=fmaf(p,v2.w,acc[11]);
    acc[12]=fmaf(p,v3.x,acc[12]); acc[13]=fmaf(p,v3.y,acc[13]);
    acc[14]=fmaf(p,v3.z,acc[14]); acc[15]=fmaf(p,v3.w,acc[15]);
  }
  float* Pb = ws + OFF_P + (size_t)((cm*KS + ks)*17)*TT + q;
  Pb[0] = l;
  #pragma unroll
  for (int d = 0; d < 16; ++d) Pb[(size_t)(1+d)*TT] = acc[d];
}

// ---------------- sum partials over ks (float4); result aliases ks=0 plane ----------------
template<int KS>
__global__ __launch_bounds__(256) void k_attn_sum(float* __restrict__ ws){
  const int idx = blockIdx.x*256 + threadIdx.x;   // 136 blocks: 2*17*1024 float4 elems
  if (idx >= 2*17*(TT/4)) return;
  const int cm = idx / (17*(TT/4));
  const int r4 = idx - cm*17*(TT/4);
  float4* P4 = reinterpret_cast<float4*>(ws + OFF_P);
  const size_t plane4 = (size_t)17*(TT/4);
  const size_t base = (size_t)cm*KS*plane4 + r4;
  float4 s = make_float4(0.f,0.f,0.f,0.f);
  #pragma unroll
  for (int ks = 0; ks < KS; ++ks){
    float4 v = P4[base + (size_t)ks*plane4];
    s.x += v.x; s.y += v.y; s.z += v.z; s.w += v.w;
  }
  P4[base] = s;   // ks=0 plane; read-before-write per thread
}

// ---------------- epilogue: /l, softmax16, W3 -> y rows ----------------
template<int KS>
__global__ __launch_bounds__(128) void k_attn_epi(
    const float* __restrict__ cm1W, const float* __restrict__ cm1b,
    const float* __restrict__ cm2W, const float* __restrict__ cm2b,
    float* __restrict__ ws){
  const int gid = blockIdx.x*128 + threadIdx.x;   // 64 blocks x 128
  const int cm = gid >> 12;
  const int q = gid & 4095;
  const float* Mb = ws + OFF_P + (size_t)cm*KS*17*TT + q;
  const float lt = Mb[0];
  float a[16];
  #pragma unroll
  for (int d = 0; d < 16; ++d) a[d] = Mb[(size_t)(1+d)*TT];
  const float invl = 1.f/lt;
  float mx = -1e30f;
  #pragma unroll
  for (int d = 0; d < 16; ++d){ a[d] *= invl; mx = fmaxf(mx, a[d]); }
  float es = 0.f;
  #pragma unroll
  for (int d = 0; d < 16; ++d){ a[d] = __expf(a[d]-mx); es += a[d]; }
  const float invs = 1.f/es;
  const float* W  = cm ? cm2W : cm1W;
  const float* Bb = cm ? cm2b : cm1b;
  #pragma unroll
  for (int c = 0; c < 16; ++c){
    float o = 0.f;
    #pragma unroll
    for (int d = 0; d < 16; ++d) o = fmaf(W[768 + c*16 + d], a[d], o);
    o = relu6f(fmaf(o, invs, Bb[48 + c]));
    ws[OFF_Y + (size_t)((cm ? 32 : 0) + c)*TT + q] = o;
  }
}

// ---------------- conv0: thread computes all 5 oc for one (oh,ow) ----------------
__global__ __launch_bounds__(256) void k_conv0(const float* __restrict__ cw0,
    const float* __restrict__ cb, float* __restrict__ ws){
  const int idx = blockIdx.x*256 + threadIdx.x;   // 384 blocks
  const int WO = 4094, HO = 24;
  if (idx >= HO*WO) return;
  const int ow = idx % WO;
  const int oh = idx / WO;
  const float* y = ws + OFF_Y;
  const float* r0 = y + (size_t)(2*oh)*TT + ow;
  const float* r1 = r0 + TT;
  float i0 = r0[0], i1 = r0[1], i2 = r0[2];
  float i3 = r1[0], i4 = r1[1], i5 = r1[2];
  #pragma unroll
  for (int oc = 0; oc < 5; ++oc){
    const float* w = cw0 + oc*6;
    float a = cb[oc];
    a = fmaf(w[0], i0, a); a = fmaf(w[1], i1, a); a = fmaf(w[2], i2, a);
    a = fmaf(w[3], i3, a); a = fmaf(w[4], i4, a); a = fmaf(w[5], i5, a);
    ws[OFF_C0 + (size_t)(oc*HO + oh)*WO + ow] = relu6f(a);
  }
}

// ---------------- conv1: (5,24,4094) -> (5,12,1023), k=(2,4), s=(2,4) ----------------
__global__ __launch_bounds__(256) void k_conv1(const float* __restrict__ cw1,
    const float* __restrict__ cb, float* __restrict__ ws){
  const int idx = blockIdx.x*256 + threadIdx.x;
  const int WO = 1023, HO = 12, WI = 4094, HI = 24;
  if (idx >= 5*HO*WO) return;
  const int ow = idx % WO; int tmp = idx / WO;
  const int oh = tmp % HO; const int oc = tmp / HO;
  const float* c0 = ws + OFF_C0;
  float a = cb[5 + oc];
  #pragma unroll
  for (int ic = 0; ic < 5; ++ic)
    #pragma unroll
    for (int kh = 0; kh < 2; ++kh)
      #pragma unroll
      for (int kw = 0; kw < 4; ++kw)
        a = fmaf(cw1[((oc*5+ic)*2+kh)*4+kw], c0[(size_t)(ic*HI + 2*oh+kh)*WI + 4*ow+kw], a);
  ws[OFF_C1 + idx] = relu6f(a);
}

// ---------------- conv2: (5,12,1023) -> (5,6,255), k=(2,4), s=(2,4) ----------------
__global__ __launch_bounds__(256) void k_conv2(const float* __restrict__ cw2,
    const float* __restrict__ cb, float* __restrict__ ws){
  const int idx = blockIdx.x*256 + threadIdx.x;
  if (idx >= 5*6*255) return;
  const int ow = idx % 255; int tmp = idx/255;
  const int oh = tmp % 6; const int oc = tmp/6;
  const float* c1 = ws + OFF_C1;
  float a = cb[10 + oc];
  #pragma unroll
  for (int ic = 0; ic < 5; ++ic)
    #pragma unroll
    for (int kh = 0; kh < 2; ++kh)
      #pragma unroll
      for (int kw = 0; kw < 4; ++kw)
        a = fmaf(cw2[((oc*5+ic)*2+kh)*4+kw], c1[(size_t)(ic*12 + 2*oh+kh)*1023 + 4*ow+kw], a);
  ws[OFF_C2 + idx] = relu6f(a);
}

// ---------------- tail: conv3 -> fc1(sigmoid, parallel) -> fc2(softmax) ----------------
__global__ __launch_bounds__(256) void k_tail(
    const float* __restrict__ cw3, const float* __restrict__ cb,
    const float* __restrict__ fc1W, const float* __restrict__ fc1b,
    const float* __restrict__ fc2W, const float* __restrict__ fc2b,
    const float* __restrict__ ws, float* __restrict__ out){
  __shared__ float c2[5*6*255];   // 30.6 KB
  __shared__ float c3[5*3*84];    // 5 KB
  __shared__ float hsm[42*15];
  const int tid = threadIdx.x;
  for (int i = tid; i < 5*6*255; i += 256) c2[i] = ws[OFF_C2 + i];
  __syncthreads();
  // conv3: k=(2,4), s=(2,3) -> (5,3,84)
  for (int idx = tid; idx < 5*3*84; idx += 256){
    const int ow = idx % 84; int tmp = idx/84;
    const int oh = tmp % 3; const int oc = tmp/3;
    float a = cb[15 + oc];
    #pragma unroll
    for (int ic = 0; ic < 5; ++ic)
      #pragma unroll
      for (int kh = 0; kh < 2; ++kh)
        #pragma unroll
        for (int kw = 0; kw < 4; ++kw)
          a = fmaf(cw3[((oc*5+ic)*2+kh)*4+kw], c2[(ic*6 + 2*oh+kh)*255 + 3*ow+kw], a);
    c3[idx] = relu6f(a);
  }
  __syncthreads();
  // fc1: 630 (sample,kx) pairs
  for (int i = tid; i < 630; i += 256){
    const int s = i / 15, kx = i % 15;
    const float* row = c3 + s*30;
    float a = fc1b[kx];
    #pragma unroll
    for (int n = 0; n < 30; ++n) a = fmaf(fc1W[kx*30+n], row[n], a);
    hsm[i] = 1.f/(1.f + __expf(-a));
  }
  __syncthreads();
  if (tid < 42){
    const float* h = hsm + tid*15;
    float l0 = fc2b[0], l1 = fc2b[1];
    #pragma unroll
    for (int kx = 0; kx < 15; ++kx){
      l0 = fmaf(fc2W[kx],    h[kx], l0);
      l1 = fmaf(fc2W[15+kx], h[kx], l1);
    }
    float mx = fmaxf(l0, l1);
    float e0 = __expf(l0-mx), e1 = __expf(l1-mx);
    float s = e0 + e1;
    out[tid*2]   = e0/s;
    out[tid*2+1] = e1/s;
  }
}

extern "C" void kernel_launch(void* const* d_in, const int* in_sizes, int n_in,
                              void* d_out, int out_size, void* d_ws, size_t ws_size,
                              hipStream_t stream){
  const float* x    = (const float*)d_in[0];
  const float* cm1W = (const float*)d_in[1];
  const float* cm1b = (const float*)d_in[2];
  const float* cm2W = (const float*)d_in[3];
  const float* cm2b = (const float*)d_in[4];
  const float* cw0  = (const float*)d_in[5];
  const float* cw1  = (const float*)d_in[6];
  const float* cw2  = (const float*)d_in[7];
  const float* cw3  = (const float*)d_in[8];
  const float* cb   = (const float*)d_in[9];
  const float* fc1W = (const float*)d_in[10];
  const float* fc1b = (const float*)d_in[11];
  const float* fc2W = (const float*)d_in[12];
  const float* fc2b = (const float*)d_in[13];
  float* ws  = (float*)d_ws;
  float* out = (float*)d_out;

  k_gpart<<<dim3(64), dim3(256), 0, stream>>>(x, ws);
  k_qkv  <<<dim3(64), dim3(128), 0, stream>>>(x, cm1W, cm1b, cm2W, cm2b, ws);

  const bool big = ws_size >= (size_t)21*1024*1024;   // capture-time constant -> deterministic
  if (big){
    k_attn_main<32><<<dim3(2*16*32), dim3(256), 0, stream>>>(ws);
    k_attn_sum <32><<<dim3(136),     dim3(256), 0, stream>>>(ws);
    k_attn_epi <32><<<dim3(64),      dim3(128), 0, stream>>>(cm1W, cm1b, cm2W, cm2b, ws);
  } else {
    k_attn_main<16><<<dim3(2*16*16), dim3(256), 0, stream>>>(ws);
    k_attn_sum <16><<<dim3(136),     dim3(256), 0, stream>>>(ws);
    k_attn_epi <16><<<dim3(64),      dim3(128), 0, stream>>>(cm1W, cm1b, cm2W, cm2b, ws);
  }

  k_conv0<<<dim3(384), dim3(256), 0, stream>>>(cw0, cb, ws);
  k_conv1<<<dim3(240), dim3(256), 0, stream>>>(cw1, cb, ws);
  k_conv2<<<dim3(30),  dim3(256), 0, stream>>>(cw2, cb, ws);
  k_tail <<<dim3(1),   dim3(256), 0, stream>>>(cw3, cb, fc1W, fc1b, fc2W, fc2b, ws, out);
}

// Round 5
// 81.877 us; speedup vs baseline: 1.8190x; 1.0013x over previous
//
#include <hip/hip_runtime.h>

#define TT 4096

// ws float offsets. KS=32 path: P end = 622592 + 2*32*17*4096 = 5,079,040 floats (19.4 MiB).
// KS=16 path: end 3,407,872 floats (13 MiB). Chosen at launch from ws_size (capture-time constant).
#define OFF_GPART 0        // [2][256][64] transposed partials
#define OFF_Q     32768    // [2][4096][16]
#define OFF_K     163840
#define OFF_V     294912
#define OFF_Y     425984   // [48][4096]
#define OFF_P     622592   // [2][KS][17][4096] flash partials (l, acc0..15), fixed-shift
#define OFF_C1    622592   // alias (conv stage runs after attn complete) (5,12,1023)
#define OFF_C2    634880   // (5,6,255)

__device__ __forceinline__ float relu6f(float v){ return fminf(fmaxf(v, 0.f), 6.f); }

// ---------------- G partials (transposed): GPART[cm][ij][blk] ----------------
__global__ __launch_bounds__(256) void k_gpart(const float* __restrict__ x, float* __restrict__ ws){
  const int b = blockIdx.x, tid = threadIdx.x;        // 64 blocks x 64 t
  const int i = tid >> 4, j = tid & 15;
  const int t0 = b*64;
  const float4* ei4 = reinterpret_cast<const float4*>(x + (size_t)(1+i)*TT + t0);
  const float4* ej4 = reinterpret_cast<const float4*>(x + (size_t)(1+j)*TT + t0);
  const float4* wA4 = reinterpret_cast<const float4*>(x + t0);
  const float4* wB4 = reinterpret_cast<const float4*>(x + (size_t)17*TT + t0);
  float gA = 0.f, gB = 0.f;
  #pragma unroll 4
  for (int u = 0; u < 16; ++u){
    float4 a = ei4[u], c = ej4[u], wa = wA4[u], wb = wB4[u];
    float p0 = a.x*c.x, p1 = a.y*c.y, p2 = a.z*c.z, p3 = a.w*c.w;
    gA = fmaf(wa.x, p0, gA); gA = fmaf(wa.y, p1, gA); gA = fmaf(wa.z, p2, gA); gA = fmaf(wa.w, p3, gA);
    gB = fmaf(wb.x, p0, gB); gB = fmaf(wb.y, p1, gB); gB = fmaf(wb.z, p2, gB); gB = fmaf(wb.w, p3, gB);
  }
  ws[OFF_GPART + (size_t)tid*64 + b]         = gA;   // cm=0
  ws[OFF_GPART + (size_t)(256+tid)*64 + b]   = gB;   // cm=1
}

// ---------------- QKV ----------------
__global__ __launch_bounds__(128) void k_qkv(const float* __restrict__ x,
    const float* __restrict__ cm1W, const float* __restrict__ cm1b,
    const float* __restrict__ cm2W, const float* __restrict__ cm2b,
    float* __restrict__ ws){
  __shared__ float4 sG4[64];
  __shared__ float4 sW0[64], sW1[64], sW2[64];
  __shared__ float sB[48];
  const int b = blockIdx.x;           // 64 blocks: cm = b>>5
  const int cm = b >> 5;
  const int tid = threadIdx.x;        // 128 threads
  {
    const float4* g4a = reinterpret_cast<const float4*>(ws + OFF_GPART + (size_t)(cm*256 + tid)*64);
    const float4* g4b = reinterpret_cast<const float4*>(ws + OFF_GPART + (size_t)(cm*256 + 128 + tid)*64);
    float g0 = 0.f, g1 = 0.f;
    #pragma unroll
    for (int u = 0; u < 16; ++u){
      float4 a = g4a[u], c = g4b[u];
      g0 += (a.x + a.y) + (a.z + a.w);
      g1 += (c.x + c.y) + (c.z + c.w);
    }
    ((float*)sG4)[tid]       = g0;
    ((float*)sG4)[tid + 128] = g1;
  }
  const float* W  = cm ? cm2W : cm1W;
  const float* Bb = cm ? cm2b : cm1b;
  ((float*)sW0)[tid]       = W[tid];
  ((float*)sW0)[tid + 128] = W[tid + 128];
  ((float*)sW1)[tid]       = W[256 + tid];
  ((float*)sW1)[tid + 128] = W[384 + tid];
  ((float*)sW2)[tid]       = W[512 + tid];
  ((float*)sW2)[tid + 128] = W[640 + tid];
  if (tid < 48) sB[tid] = Bb[tid];
  __syncthreads();

  const int t = (b & 31)*128 + tid;
  float e[16], p[16], w2[16];
  const float wav = x[(size_t)(cm ? 17 : 0)*TT + t];
  #pragma unroll
  for (int d = 0; d < 16; ++d){ e[d] = x[(size_t)(1+d)*TT + t]; p[d] = wav * e[d]; }

  #pragma unroll
  for (int c = 0; c < 16; ++c){
    float a = 0.f;
    #pragma unroll
    for (int dv = 0; dv < 4; ++dv){
      float4 gv = sG4[c*4+dv];
      a = fmaf(gv.x, p[4*dv+0], a); a = fmaf(gv.y, p[4*dv+1], a);
      a = fmaf(gv.z, p[4*dv+2], a); a = fmaf(gv.w, p[4*dv+3], a);
    }
    w2[c] = a;
  }
  float q[16], kk[16], vv[16];
  #pragma unroll
  for (int c = 0; c < 16; ++c){
    float aq = sB[c], ak = sB[16+c], av = sB[32+c];
    #pragma unroll
    for (int dv = 0; dv < 4; ++dv){
      float4 w0 = sW0[c*4+dv], w1 = sW1[c*4+dv], w3 = sW2[c*4+dv];
      aq = fmaf(w0.x, e[4*dv+0], aq);  aq = fmaf(w0.y, e[4*dv+1], aq);
      aq = fmaf(w0.z, e[4*dv+2], aq);  aq = fmaf(w0.w, e[4*dv+3], aq);
      ak = fmaf(w1.x, w2[4*dv+0], ak); ak = fmaf(w1.y, w2[4*dv+1], ak);
      ak = fmaf(w1.z, w2[4*dv+2], ak); ak = fmaf(w1.w, w2[4*dv+3], ak);
      av = fmaf(w3.x, w2[4*dv+0], av); av = fmaf(w3.y, w2[4*dv+1], av);
      av = fmaf(w3.z, w2[4*dv+2], av); av = fmaf(w3.w, w2[4*dv+3], av);
    }
    q[c] = relu6f(aq); kk[c] = relu6f(ak); vv[c] = relu6f(av);
  }
  float* Qp = ws + OFF_Q + ((size_t)cm*TT + t)*16;
  float* Kp = ws + OFF_K + ((size_t)cm*TT + t)*16;
  float* Vp = ws + OFF_V + ((size_t)cm*TT + t)*16;
  #pragma unroll
  for (int dv = 0; dv < 4; ++dv){
    reinterpret_cast<float4*>(Qp)[dv] = make_float4(q[4*dv],  q[4*dv+1],  q[4*dv+2],  q[4*dv+3]);
    reinterpret_cast<float4*>(Kp)[dv] = make_float4(kk[4*dv], kk[4*dv+1], kk[4*dv+2], kk[4*dv+3]);
    reinterpret_cast<float4*>(Vp)[dv] = make_float4(vv[4*dv], vv[4*dv+1], vv[4*dv+2], vv[4*dv+3]);
  }
  if (cm == 0){
    #pragma unroll
    for (int d = 0; d < 16; ++d) ws[OFF_Y + (size_t)(16+d)*TT + t] = e[d];
  }
}

// ---------------- attention main: LDS-staged K/V (broadcast reads), unroll-4 ILP ----------------
template<int KS>
__global__ __launch_bounds__(256, 4) void k_attn_main(float* __restrict__ ws){
  constexpr int KPB = TT/KS;
  __shared__ float4 sK[KPB*4];   // [key][4 x float4]
  __shared__ float4 sV[KPB*4];
  const int b = blockIdx.x;           // [cm][qblk 16][ks KS]
  const int cm = b / (16*KS);
  const int rem = b % (16*KS);
  const int qblk = rem / KS;
  const int ks = rem % KS;
  const int tid = threadIdx.x;
  const int j0 = ks*KPB;

  // stage K/V slice (coalesced)
  {
    const float4* Ksrc = reinterpret_cast<const float4*>(ws + OFF_K + ((size_t)cm*TT + j0)*16);
    const float4* Vsrc = reinterpret_cast<const float4*>(ws + OFF_V + ((size_t)cm*TT + j0)*16);
    #pragma unroll
    for (int i = tid; i < KPB*4; i += 256){ sK[i] = Ksrc[i]; sV[i] = Vsrc[i]; }
  }
  __syncthreads();

  const int q = qblk*256 + tid;
  float qr[16];
  {
    const float4* q4 = reinterpret_cast<const float4*>(ws + OFF_Q + ((size_t)cm*TT + q)*16);
    float4 a = q4[0], bq = q4[1], c = q4[2], d = q4[3];
    qr[0]=a.x;  qr[1]=a.y;  qr[2]=a.z;  qr[3]=a.w;
    qr[4]=bq.x; qr[5]=bq.y; qr[6]=bq.z; qr[7]=bq.w;
    qr[8]=c.x;  qr[9]=c.y;  qr[10]=c.z; qr[11]=c.w;
    qr[12]=d.x; qr[13]=d.y; qr[14]=d.z; qr[15]=d.w;
  }
  float l = 0.f, acc[16];
  #pragma unroll
  for (int d = 0; d < 16; ++d) acc[d] = 0.f;

  for (int k0 = 0; k0 < KPB; k0 += 4){
    float s[4];
    #pragma unroll
    for (int u = 0; u < 4; ++u){
      float4 k0v = sK[(k0+u)*4+0], k1v = sK[(k0+u)*4+1], k2v = sK[(k0+u)*4+2], k3v = sK[(k0+u)*4+3];
      float t0 = qr[0]*k0v.x;
      float t1 = qr[1]*k0v.y;
      t0=fmaf(qr[2],k0v.z,t0);  t1=fmaf(qr[3],k0v.w,t1);
      t0=fmaf(qr[4],k1v.x,t0);  t1=fmaf(qr[5],k1v.y,t1);
      t0=fmaf(qr[6],k1v.z,t0);  t1=fmaf(qr[7],k1v.w,t1);
      t0=fmaf(qr[8],k2v.x,t0);  t1=fmaf(qr[9],k2v.y,t1);
      t0=fmaf(qr[10],k2v.z,t0); t1=fmaf(qr[11],k2v.w,t1);
      t0=fmaf(qr[12],k3v.x,t0); t1=fmaf(qr[13],k3v.y,t1);
      t0=fmaf(qr[14],k3v.z,t0); t1=fmaf(qr[15],k3v.w,t1);
      s[u] = t0 + t1;
    }
    float p[4];
    #pragma unroll
    for (int u = 0; u < 4; ++u){
      p[u] = __expf(fminf(s[u], 100.f) - 32.f);   // fixed shift -> linear partials
    }
    l += (p[0]+p[1]) + (p[2]+p[3]);
    #pragma unroll
    for (int u = 0; u < 4; ++u){
      float4 v0 = sV[(k0+u)*4+0], v1 = sV[(k0+u)*4+1], v2 = sV[(k0+u)*4+2], v3 = sV[(k0+u)*4+3];
      float pu = p[u];
      acc[0]=fmaf(pu,v0.x,acc[0]);  acc[1]=fmaf(pu,v0.y,acc[1]);
      acc[2]=fmaf(pu,v0.z,acc[2]);  acc[3]=fmaf(pu,v0.w,acc[3]);
      acc[4]=fmaf(pu,v1.x,acc[4]);  acc[5]=fmaf(pu,v1.y,acc[5]);
      acc[6]=fmaf(pu,v1.z,acc[6]);  acc[7]=fmaf(pu,v1.w,acc[7]);
      acc[8]=fmaf(pu,v2.x,acc[8]);  acc[9]=fmaf(pu,v2.y,acc[9]);
      acc[10]=fmaf(pu,v2.z,acc[10]); acc[11]=fmaf(pu,v2.w,acc[11]);
      acc[12]=fmaf(pu,v3.x,acc[12]); acc[13]=fmaf(pu,v3.y,acc[13]);
      acc[14]=fmaf(pu,v3.z,acc[14]); acc[15]=fmaf(pu,v3.w,acc[15]);
    }
  }
  float* Pb = ws + OFF_P + (size_t)((cm*KS + ks)*17)*TT + q;
  Pb[0] = l;
  #pragma unroll
  for (int d = 0; d < 16; ++d) Pb[(size_t)(1+d)*TT] = acc[d];
}

// ---------------- sum partials over ks (float4); result aliases ks=0 plane ----------------
template<int KS>
__global__ __launch_bounds__(256) void k_attn_sum(float* __restrict__ ws){
  const int idx = blockIdx.x*256 + threadIdx.x;   // 136 blocks: 2*17*1024 float4 elems
  if (idx >= 2*17*(TT/4)) return;
  const int cm = idx / (17*(TT/4));
  const int r4 = idx - cm*17*(TT/4);
  float4* P4 = reinterpret_cast<float4*>(ws + OFF_P);
  const size_t plane4 = (size_t)17*(TT/4);
  const size_t base = (size_t)cm*KS*plane4 + r4;
  float4 s = make_float4(0.f,0.f,0.f,0.f);
  #pragma unroll
  for (int ks = 0; ks < KS; ++ks){
    float4 v = P4[base + (size_t)ks*plane4];
    s.x += v.x; s.y += v.y; s.z += v.z; s.w += v.w;
  }
  P4[base] = s;   // ks=0 plane; read-before-write per thread
}

// ---------------- epilogue: /l, softmax16, W3 -> y rows ----------------
template<int KS>
__global__ __launch_bounds__(128) void k_attn_epi(
    const float* __restrict__ cm1W, const float* __restrict__ cm1b,
    const float* __restrict__ cm2W, const float* __restrict__ cm2b,
    float* __restrict__ ws){
  const int gid = blockIdx.x*128 + threadIdx.x;   // 64 blocks x 128
  const int cm = gid >> 12;
  const int q = gid & 4095;
  const float* Mb = ws + OFF_P + (size_t)cm*KS*17*TT + q;
  const float lt = Mb[0];
  float a[16];
  #pragma unroll
  for (int d = 0; d < 16; ++d) a[d] = Mb[(size_t)(1+d)*TT];
  const float invl = 1.f/lt;
  float mx = -1e30f;
  #pragma unroll
  for (int d = 0; d < 16; ++d){ a[d] *= invl; mx = fmaxf(mx, a[d]); }
  float es = 0.f;
  #pragma unroll
  for (int d = 0; d < 16; ++d){ a[d] = __expf(a[d]-mx); es += a[d]; }
  const float invs = 1.f/es;
  const float* W  = cm ? cm2W : cm1W;
  const float* Bb = cm ? cm2b : cm1b;
  #pragma unroll
  for (int c = 0; c < 16; ++c){
    float o = 0.f;
    #pragma unroll
    for (int d = 0; d < 16; ++d) o = fmaf(W[768 + c*16 + d], a[d], o);
    o = relu6f(fmaf(o, invs, Bb[48 + c]));
    ws[OFF_Y + (size_t)((cm ? 32 : 0) + c)*TT + q] = o;
  }
}

// ---------------- fused conv0+conv1: Y(48,4096) -> C1(5,12,1023), recompute C0 patch ----------------
__global__ __launch_bounds__(256) void k_conv01(const float* __restrict__ cw0,
    const float* __restrict__ cw1, const float* __restrict__ cb, float* __restrict__ ws){
  const int idx = blockIdx.x*256 + threadIdx.x;   // 240 blocks
  const int WO = 1023, HO = 12;
  if (idx >= 5*HO*WO) return;
  const int ow = idx % WO; int tmp = idx / WO;
  const int oh = tmp % HO; const int oc = tmp / HO;
  const float* y = ws + OFF_Y;
  // Y patch: rows 4*oh .. 4*oh+3, cols 4*ow .. 4*ow+6
  float yp[4][7];
  #pragma unroll
  for (int r = 0; r < 4; ++r){
    const float* yr = y + (size_t)(4*oh + r)*TT + 4*ow;
    #pragma unroll
    for (int cx = 0; cx < 7; ++cx) yp[r][cx] = yr[cx];
  }
  float a = cb[5 + oc];
  #pragma unroll
  for (int ic = 0; ic < 5; ++ic){
    const float* w0 = cw0 + ic*6;
    const float* w1 = cw1 + ((oc*5+ic)*2)*4;
    #pragma unroll
    for (int kh = 0; kh < 2; ++kh){
      #pragma unroll
      for (int kw = 0; kw < 4; ++kw){
        // c0(ic, 2*oh+kh, 4*ow+kw): rows 2*kh..2*kh+1, cols kw..kw+2 of patch
        float c0 = cb[ic];
        c0 = fmaf(w0[0], yp[2*kh][kw],   c0);
        c0 = fmaf(w0[1], yp[2*kh][kw+1], c0);
        c0 = fmaf(w0[2], yp[2*kh][kw+2], c0);
        c0 = fmaf(w0[3], yp[2*kh+1][kw],   c0);
        c0 = fmaf(w0[4], yp[2*kh+1][kw+1], c0);
        c0 = fmaf(w0[5], yp[2*kh+1][kw+2], c0);
        c0 = relu6f(c0);
        a = fmaf(w1[kh*4+kw], c0, a);
      }
    }
  }
  ws[OFF_C1 + idx] = relu6f(a);
}

// ---------------- conv2: (5,12,1023) -> (5,6,255), k=(2,4), s=(2,4) ----------------
__global__ __launch_bounds__(256) void k_conv2(const float* __restrict__ cw2,
    const float* __restrict__ cb, float* __restrict__ ws){
  const int idx = blockIdx.x*256 + threadIdx.x;
  if (idx >= 5*6*255) return;
  const int ow = idx % 255; int tmp = idx/255;
  const int oh = tmp % 6; const int oc = tmp/6;
  const float* c1 = ws + OFF_C1;
  float a = cb[10 + oc];
  #pragma unroll
  for (int ic = 0; ic < 5; ++ic)
    #pragma unroll
    for (int kh = 0; kh < 2; ++kh)
      #pragma unroll
      for (int kw = 0; kw < 4; ++kw)
        a = fmaf(cw2[((oc*5+ic)*2+kh)*4+kw], c1[(size_t)(ic*12 + 2*oh+kh)*1023 + 4*ow+kw], a);
  ws[OFF_C2 + idx] = relu6f(a);
}

// ---------------- tail: conv3 -> fc1(sigmoid, parallel) -> fc2(softmax) ----------------
__global__ __launch_bounds__(256) void k_tail(
    const float* __restrict__ cw3, const float* __restrict__ cb,
    const float* __restrict__ fc1W, const float* __restrict__ fc1b,
    const float* __restrict__ fc2W, const float* __restrict__ fc2b,
    const float* __restrict__ ws, float* __restrict__ out){
  __shared__ float c2[5*6*255];   // 30.6 KB
  __shared__ float c3[5*3*84];    // 5 KB
  __shared__ float hsm[42*15];
  const int tid = threadIdx.x;
  for (int i = tid; i < 5*6*255; i += 256) c2[i] = ws[OFF_C2 + i];
  __syncthreads();
  // conv3: k=(2,4), s=(2,3) -> (5,3,84)
  for (int idx = tid; idx < 5*3*84; idx += 256){
    const int ow = idx % 84; int tmp = idx/84;
    const int oh = tmp % 3; const int oc = tmp/3;
    float a = cb[15 + oc];
    #pragma unroll
    for (int ic = 0; ic < 5; ++ic)
      #pragma unroll
      for (int kh = 0; kh < 2; ++kh)
        #pragma unroll
        for (int kw = 0; kw < 4; ++kw)
          a = fmaf(cw3[((oc*5+ic)*2+kh)*4+kw], c2[(ic*6 + 2*oh+kh)*255 + 3*ow+kw], a);
    c3[idx] = relu6f(a);
  }
  __syncthreads();
  // fc1: 630 (sample,kx) pairs
  for (int i = tid; i < 630; i += 256){
    const int s = i / 15, kx = i % 15;
    const float* row = c3 + s*30;
    float a = fc1b[kx];
    #pragma unroll
    for (int n = 0; n < 30; ++n) a = fmaf(fc1W[kx*30+n], row[n], a);
    hsm[i] = 1.f/(1.f + __expf(-a));
  }
  __syncthreads();
  if (tid < 42){
    const float* h = hsm + tid*15;
    float l0 = fc2b[0], l1 = fc2b[1];
    #pragma unroll
    for (int kx = 0; kx < 15; ++kx){
      l0 = fmaf(fc2W[kx],    h[kx], l0);
      l1 = fmaf(fc2W[15+kx], h[kx], l1);
    }
    float mx = fmaxf(l0, l1);
    float e0 = __expf(l0-mx), e1 = __expf(l1-mx);
    float s = e0 + e1;
    out[tid*2]   = e0/s;
    out[tid*2+1] = e1/s;
  }
}

extern "C" void kernel_launch(void* const* d_in, const int* in_sizes, int n_in,
                              void* d_out, int out_size, void* d_ws, size_t ws_size,
                              hipStream_t stream){
  const float* x    = (const float*)d_in[0];
  const float* cm1W = (const float*)d_in[1];
  const float* cm1b = (const float*)d_in[2];
  const float* cm2W = (const float*)d_in[3];
  const float* cm2b = (const float*)d_in[4];
  const float* cw0  = (const float*)d_in[5];
  const float* cw1  = (const float*)d_in[6];
  const float* cw2  = (const float*)d_in[7];
  const float* cw3  = (const float*)d_in[8];
  const float* cb   = (const float*)d_in[9];
  const float* fc1W = (const float*)d_in[10];
  const float* fc1b = (const float*)d_in[11];
  const float* fc2W = (const float*)d_in[12];
  const float* fc2b = (const float*)d_in[13];
  float* ws  = (float*)d_ws;
  float* out = (float*)d_out;

  k_gpart<<<dim3(64), dim3(256), 0, stream>>>(x, ws);
  k_qkv  <<<dim3(64), dim3(128), 0, stream>>>(x, cm1W, cm1b, cm2W, cm2b, ws);

  const bool big = ws_size >= (size_t)21*1024*1024;   // capture-time constant -> deterministic
  if (big){
    k_attn_main<32><<<dim3(2*16*32), dim3(256), 0, stream>>>(ws);
    k_attn_sum <32><<<dim3(136),     dim3(256), 0, stream>>>(ws);
    k_attn_epi <32><<<dim3(64),      dim3(128), 0, stream>>>(cm1W, cm1b, cm2W, cm2b, ws);
  } else {
    k_attn_main<16><<<dim3(2*16*16), dim3(256), 0, stream>>>(ws);
    k_attn_sum <16><<<dim3(136),     dim3(256), 0, stream>>>(ws);
    k_attn_epi <16><<<dim3(64),      dim3(128), 0, stream>>>(cm1W, cm1b, cm2W, cm2b, ws);
  }

  k_conv01<<<dim3(240), dim3(256), 0, stream>>>(cw0, cw1, cb, ws);
  k_conv2 <<<dim3(30),  dim3(256), 0, stream>>>(cw2, cb, ws);
  k_tail  <<<dim3(1),   dim3(256), 0, stream>>>(cw3, cb, fc1W, fc1b, fc2W, fc2b, ws, out);
}